// Round 7
// baseline (229.788 us; speedup 1.0000x reference)
//
#include <hip/hip_runtime.h>
#include <hip/hip_fp16.h>
#include <cstdint>
#include <cstddef>

// ---------------------------------------------------------------------------
// SelfAttentionV2: out = softmax((x Wq + bq)(x Wk + bk)^T / 32) (x Wv + bv)
// N=4096, D=1024. fp32 in/out, fp16 MFMA internal.
// R19: schedule family exhausted (R12/R14/R16/R18 all ~45us / 28% MfmaUtil).
//   Theory pivot: OCCUPANCY. All prior cores: 128-reg acc -> ~230 unified ->
//   2 waves/SIMD, big tiles 1 block/CU, all waves phase-locked -> no
//   independent-wave overlap (m114 mechanism). m97 blueprint: 128x128 tile,
//   4 waves x 64x64 (acc 64 regs), BK=64 single-buffer 32KB LDS, plain
//   2-barrier __syncthreads loop, ~3 blocks/CU = 912 TF measured on-chip.
//   - s_kernel/pv_kernel -> gemm128_core (m97 exact), grids 1024,
//     __launch_bounds__(256,3) caps unified regs ~170 (watch WRITE_SIZE
//     for spill signature).
//   - qkv (gemm_wide 512-block mixed-K), prep, combine_v, add_inv verbatim.
//   rowsum partials stay 64/row: idx = nt*2 + n-wave.
// ---------------------------------------------------------------------------

#define NTOK 4096
#define DIM  1024

typedef _Float16 half8  __attribute__((ext_vector_type(8)));
typedef _Float16 half4v __attribute__((ext_vector_type(4)));
typedef float    floatx4 __attribute__((ext_vector_type(4)));

#define GLOBAL_AS __attribute__((address_space(1)))
#define LDS_AS    __attribute__((address_space(3)))

__device__ __forceinline__ void lds_load16(const _Float16* gsrc, _Float16* ldst) {
    __builtin_amdgcn_global_load_lds((GLOBAL_AS void*)gsrc, (LDS_AS void*)ldst, 16, 0, 0);
}

// ---------------------------------------------------------------------------
// WIDE 4-WAVE NT GEMM core (verbatim R4/R9/R11, verified) — used by qkv.
// ---------------------------------------------------------------------------
__device__ __forceinline__ void gemm_wide_core(const _Float16* __restrict__ A,
                                               const _Float16* __restrict__ B,
                                               int K, int lda, int ldb,
                                               int m0, int n0,
                                               _Float16* ldsA, _Float16* ldsB,
                                               floatx4 acc[4][8])
{
    const int t    = threadIdx.x;
    const int lane = t & 63;
    const int wid  = t >> 6;
    const int wm   = (wid >> 1) * 64;
    const int wn   = (wid & 1) * 128;
    const int lrow = lane & 15;
    const int q    = lane >> 4;
    const int xk   = lrow & 7;

    const _Float16* asrc[4]; _Float16* adst[4];
    const _Float16* bsrc[8]; _Float16* bdst[8];
    #pragma unroll
    for (int i = 0; i < 4; ++i) {
        const int p = t + 256 * i, row = p >> 3;
        const int col = ((p & 7) ^ (row & 7)) * 8;
        asrc[i] = A + (size_t)(m0 + row) * lda + col;
        adst[i] = ldsA + p * 8;
    }
    #pragma unroll
    for (int i = 0; i < 8; ++i) {
        const int p = t + 256 * i, row = p >> 3;
        const int col = ((p & 7) ^ (row & 7)) * 8;
        bsrc[i] = B + (size_t)(n0 + row) * ldb + col;
        bdst[i] = ldsB + p * 8;
    }

    const _Float16* fa = ldsA + (wm + lrow) * 64;
    const _Float16* fb = ldsB + (wn + lrow) * 64;

    for (int k0 = 0; k0 < K; k0 += 64) {
        #pragma unroll
        for (int i = 0; i < 4; ++i) lds_load16(asrc[i] + k0, adst[i]);
        #pragma unroll
        for (int i = 0; i < 8; ++i) lds_load16(bsrc[i] + k0, bdst[i]);
        __syncthreads();

        #pragma unroll
        for (int s = 0; s < 2; ++s) {
            const int co = (((s * 4 + q) ^ xk) * 8);
            half8 af[4], bf[8];
            #pragma unroll
            for (int i = 0; i < 4; ++i) af[i] = *(const half8*)(fa + i * 1024 + co);
            #pragma unroll
            for (int i = 0; i < 8; ++i) bf[i] = *(const half8*)(fb + i * 1024 + co);
            #pragma unroll
            for (int ni = 0; ni < 8; ++ni)
                #pragma unroll
                for (int mi = 0; mi < 4; ++mi)
                    acc[mi][ni] = __builtin_amdgcn_mfma_f32_16x16x32_f16(
                        af[mi], bf[ni], acc[mi][ni], 0, 0, 0);
        }
        __syncthreads();
    }
}

// ---------------------------------------------------------------------------
// m97-blueprint core: 128x128 tile, 256 thr, 4 waves (2x2) each 64x64,
// acc[4][4] (64 regs), BK=64 single-buffered 32KB LDS, 2-barrier loop.
// A: M x K row-major (lda), B: N x K row-major (ldb); C = A.B^T at (m0,n0).
// ---------------------------------------------------------------------------
__device__ __forceinline__ void gemm128_core(const _Float16* __restrict__ A,
                                             const _Float16* __restrict__ B,
                                             int K, int lda, int ldb,
                                             int m0, int n0,
                                             _Float16* ldsA, _Float16* ldsB,
                                             floatx4 acc[4][4])
{
    const int t    = threadIdx.x;        // 0..255
    const int lane = t & 63;
    const int wid  = t >> 6;             // 0..3
    const int wm   = (wid >> 1) * 64;
    const int wn   = (wid & 1) * 64;
    const int lrow = lane & 15;
    const int q    = lane >> 4;
    const int xk   = lrow & 7;

    // Staging: p = t + 256*i (i=0..3) -> row p>>3 (0..127), c8 = p&7.
    // XOR swizzle on global source col; LDS dst linear (rule #21 pair).
    const _Float16* asrc[4]; _Float16* adst[4];
    const _Float16* bsrc[4]; _Float16* bdst[4];
    #pragma unroll
    for (int i = 0; i < 4; ++i) {
        const int p = t + 256 * i, row = p >> 3, c8 = p & 7;
        const int col = (c8 ^ (row & 7)) * 8;
        asrc[i] = A + (size_t)(m0 + row) * lda + col;
        adst[i] = ldsA + row * 64 + c8 * 8;
        bsrc[i] = B + (size_t)(n0 + row) * ldb + col;
        bdst[i] = ldsB + row * 64 + c8 * 8;
    }

    const _Float16* fa = ldsA + (wm + lrow) * 64;
    const _Float16* fb = ldsB + (wn + lrow) * 64;

    for (int k0 = 0; k0 < K; k0 += 64) {
        #pragma unroll
        for (int i = 0; i < 4; ++i) {
            lds_load16(asrc[i] + k0, adst[i]);
            lds_load16(bsrc[i] + k0, bdst[i]);
        }
        __syncthreads();   // compiler drains vmcnt here (m97 structure)

        #pragma unroll
        for (int s = 0; s < 2; ++s) {
            const int co = (((s * 4 + q) ^ xk) * 8);
            half8 af[4], bf[4];
            #pragma unroll
            for (int i = 0; i < 4; ++i) af[i] = *(const half8*)(fa + i * 1024 + co);
            #pragma unroll
            for (int i = 0; i < 4; ++i) bf[i] = *(const half8*)(fb + i * 1024 + co);
            #pragma unroll
            for (int ni = 0; ni < 4; ++ni)
                #pragma unroll
                for (int mi = 0; mi < 4; ++mi)
                    acc[mi][ni] = __builtin_amdgcn_mfma_f32_16x16x32_f16(
                        af[mi], bf[ni], acc[mi][ni], 0, 0, 0);
        }
        __syncthreads();   // readers done before next stage overwrites
    }
}

// ---------------------------------------------------------------------------
// K0: prep (verbatim R9 body, grid 3072).
// ---------------------------------------------------------------------------
__global__ void __launch_bounds__(128) prep_kernel(const float* __restrict__ x,
                                                   const float* __restrict__ W0,
                                                   const float* __restrict__ W1,
                                                   const float* __restrict__ W2,
                                                   _Float16* __restrict__ xh,
                                                   _Float16* __restrict__ Wt)
{
    __shared__ float tile[32 * 33];
    const int t = threadIdx.x;
    const int G = gridDim.x;

    for (size_t idx = (size_t)blockIdx.x * 128 + t; idx < (size_t)NTOK * DIM / 4;
         idx += (size_t)G * 128) {
        size_t i = idx * 4;
        float4 v = *(const float4*)(x + i);
        half4v h;
        h[0] = (_Float16)v.x; h[1] = (_Float16)v.y;
        h[2] = (_Float16)v.z; h[3] = (_Float16)v.w;
        *(half4v*)(xh + i) = h;
    }

    const int tx = t & 31, ty = t >> 5;   // ty in [0,4)
    for (int w = blockIdx.x; w < 3072; w += G) {
        const int z = w >> 10, r = w & 1023;
        const int nb = (r & 31) * 32, kb = (r >> 5) * 32;
        const float* W = (z == 0) ? W0 : (z == 1) ? W1 : W2;
        _Float16* outw = Wt + (size_t)z * DIM * DIM;
        #pragma unroll
        for (int i = 0; i < 32; i += 4)
            tile[(ty + i) * 33 + tx] = W[(size_t)(kb + ty + i) * DIM + nb + tx];
        __syncthreads();
        #pragma unroll
        for (int i = 0; i < 32; i += 4)
            outw[(size_t)(nb + ty + i) * DIM + kb + tx] =
                (_Float16)tile[tx * 33 + ty + i];
        __syncthreads();
    }
}

// ---------------------------------------------------------------------------
// K1: QKV mixed-K wide grid (verbatim R9/R12, verified; 512 blocks = 2/CU).
// ---------------------------------------------------------------------------
__global__ void __launch_bounds__(256, 2)
qkv_kernel(const _Float16* __restrict__ xh,
           const _Float16* __restrict__ Wt,
           const float* __restrict__ bq,
           const float* __restrict__ bk,
           const float* __restrict__ bv,
           _Float16* __restrict__ qh,
           _Float16* __restrict__ kh,
           _Float16* __restrict__ vt0,
           _Float16* __restrict__ vt1)
{
    __shared__ _Float16 ldsA[128 * 64];
    __shared__ _Float16 ldsB[256 * 64];

    const int b = blockIdx.x;

    const _Float16* A; const _Float16* B;
    const float* bias; _Float16* outm;
    int m0, n0, ldc, K, kstart; bool bias_by_row, do_bias;

    if (b < 256) {
        const int z = b >> 7;            // 0:q 1:k
        const int g = b & 127;
        const int xcd = g & 7;
        const int j   = g >> 3;          // 0..15
        const int mt  = xcd * 4 + (j & 3);   // 32 m-tiles
        const int nt  = j >> 2;              // 4 n-tiles of 256
        m0 = mt * 128; n0 = nt * 256; ldc = DIM;
        K = DIM; kstart = 0; bias_by_row = false; do_bias = true;
        A = xh;
        B = (z == 0) ? Wt : Wt + DIM * DIM;
        bias = (z == 0) ? bq : bk;
        outm = (z == 0) ? qh : kh;
    } else {
        const int h = (b - 256) >> 7;    // k-half 0/1
        const int g = b & 127;
        const int xcd = g & 7;
        const int j   = g >> 3;          // 0..15
        m0 = xcd * 128;                  // 8 m-tiles (d-dim)
        n0 = j * 256;                    // 16 n-tiles (tokens)
        ldc = NTOK;
        K = DIM / 2; kstart = h * (DIM / 2);
        bias_by_row = true; do_bias = (h == 0);
        A = Wt + 2 * DIM * DIM; B = xh; bias = bv;
        outm = (h == 0) ? vt0 : vt1;
    }

    floatx4 acc[4][8];
    #pragma unroll
    for (int mi = 0; mi < 4; ++mi)
        #pragma unroll
        for (int ni = 0; ni < 8; ++ni)
            #pragma unroll
            for (int r = 0; r < 4; ++r) acc[mi][ni][r] = 0.0f;

    gemm_wide_core(A + kstart, B + kstart, K, DIM, DIM, m0, n0, ldsA, ldsB, acc);

    const int lane = threadIdx.x & 63;
    const int wid  = threadIdx.x >> 6;
    const int wm   = (wid >> 1) * 64;
    const int wn   = (wid & 1) * 128;
    const int lrow = lane & 15;
    const int q    = lane >> 4;
    #pragma unroll
    for (int mi = 0; mi < 4; ++mi) {
        #pragma unroll
        for (int ni = 0; ni < 8; ++ni) {
            const int gm = m0 + wm + mi * 16 + q * 4;
            const int gn = n0 + wn + ni * 16 + lrow;
            const float bcol = (!do_bias || bias_by_row) ? 0.0f : bias[gn];
            #pragma unroll
            for (int r = 0; r < 4; ++r) {
                float bb = do_bias ? (bias_by_row ? bias[gm + r] : bcol) : 0.0f;
                outm[(size_t)(gm + r) * ldc + gn] = (_Float16)(acc[mi][ni][r] + bb);
            }
        }
    }
}

// ---------------------------------------------------------------------------
// K2: combine v partials: vt = vt0 + vt1 (verbatim R9).
// ---------------------------------------------------------------------------
__global__ void __launch_bounds__(256) combine_v(const _Float16* __restrict__ vt0,
                                                 const _Float16* __restrict__ vt1,
                                                 _Float16* __restrict__ vt)
{
    size_t i = ((size_t)blockIdx.x * 256 + threadIdx.x) * 8;
    half8 a = *(const half8*)(vt0 + i);
    half8 b = *(const half8*)(vt1 + i);
    half8 o;
    #pragma unroll
    for (int k = 0; k < 8; ++k) o[k] = (_Float16)((float)a[k] + (float)b[k]);
    *(half8*)(vt + i) = o;
}

// ---------------------------------------------------------------------------
// K3: S-GEMM + fused exp + partial rowsums — m97 128x128 core.
// grid 1024 (32mt x 32nt), XCD-banded, 256 thr, target 3 blocks/CU.
// rowsum partials: 64 per row = 32 nt x 2 n-waves.
// ---------------------------------------------------------------------------
__global__ void __launch_bounds__(256, 3) s_kernel(const _Float16* __restrict__ qh,
                                                   const _Float16* __restrict__ kh,
                                                   _Float16* __restrict__ P,
                                                   float* __restrict__ rowsum_part)
{
    __shared__ _Float16 ldsA[128 * 64];   // 16 KiB
    __shared__ _Float16 ldsB[128 * 64];   // 16 KiB

    const int f   = blockIdx.x;
    const int xcd = f & 7;
    const int j   = f >> 3;              // 0..127
    const int mt  = xcd * 4 + (j & 3);   // 32 m-tiles of 128
    const int nt  = j >> 2;              // 32 n-tiles of 128
    const int m0  = mt * 128;
    const int n0  = nt * 128;

    floatx4 acc[4][4];
    #pragma unroll
    for (int mi = 0; mi < 4; ++mi)
        #pragma unroll
        for (int ni = 0; ni < 4; ++ni)
            #pragma unroll
            for (int r = 0; r < 4; ++r) acc[mi][ni][r] = 0.0f;

    gemm128_core(qh, kh, DIM, DIM, DIM, m0, n0, ldsA, ldsB, acc);

    const int lane = threadIdx.x & 63;
    const int wid  = threadIdx.x >> 6;
    const int wm   = (wid >> 1) * 64;
    const int wn   = (wid & 1) * 64;
    const int lrow = lane & 15;
    const int q    = lane >> 4;

    #pragma unroll
    for (int mi = 0; mi < 4; ++mi) {
        #pragma unroll
        for (int r = 0; r < 4; ++r) {
            const int gm = m0 + wm + mi * 16 + q * 4 + r;
            float rs = 0.0f;
            #pragma unroll
            for (int ni = 0; ni < 4; ++ni) {
                const int gn = n0 + wn + ni * 16 + lrow;
                float e = __expf(acc[mi][ni][r] * 0.03125f - 8.0f);
                P[(size_t)gm * NTOK + gn] = (_Float16)e;
                rs += e;
            }
            rs += __shfl_xor(rs, 1, 64);
            rs += __shfl_xor(rs, 2, 64);
            rs += __shfl_xor(rs, 4, 64);
            rs += __shfl_xor(rs, 8, 64);
            if (lrow == 0) rowsum_part[(size_t)gm * 64 + nt * 2 + (wid & 1)] = rs;
        }
    }
}

// ---------------------------------------------------------------------------
// K4: PV split-K=4 — m97 128x128 core. grid 1024 (4z x 32mt x 8nt).
// z=0 -> fp32 out raw; z=1..3 -> fp16 partials.
// ---------------------------------------------------------------------------
__global__ void __launch_bounds__(256, 3) pv_kernel(const _Float16* __restrict__ P,
                                                    const _Float16* __restrict__ vt,
                                                    float* __restrict__ out,
                                                    _Float16* __restrict__ P1,
                                                    _Float16* __restrict__ P2,
                                                    _Float16* __restrict__ P3)
{
    __shared__ _Float16 ldsA[128 * 64];
    __shared__ _Float16 ldsB[128 * 64];

    const int b   = blockIdx.x;
    const int z   = b >> 8;              // 0..3
    const int g   = b & 255;
    const int xcd = g & 7;
    const int j   = g >> 3;              // 0..31
    const int mt  = xcd * 4 + (j & 3);   // 32 m-tiles of 128 (tokens)
    const int nt  = j >> 2;              // 8 n-tiles of 128 (dim)
    const int m0  = mt * 128;
    const int n0  = nt * 128;
    const int kstart = z * (NTOK / 4);

    floatx4 acc[4][4];
    #pragma unroll
    for (int mi = 0; mi < 4; ++mi)
        #pragma unroll
        for (int ni = 0; ni < 4; ++ni)
            #pragma unroll
            for (int r = 0; r < 4; ++r) acc[mi][ni][r] = 0.0f;

    gemm128_core(P + kstart, vt + kstart, NTOK / 4, NTOK, NTOK, m0, n0,
                 ldsA, ldsB, acc);

    const int lane = threadIdx.x & 63;
    const int wid  = threadIdx.x >> 6;
    const int wm   = (wid >> 1) * 64;
    const int wn   = (wid & 1) * 64;
    const int lrow = lane & 15;
    const int q    = lane >> 4;

    _Float16* ph = (z == 1) ? P1 : (z == 2) ? P2 : P3;
    #pragma unroll
    for (int mi = 0; mi < 4; ++mi) {
        #pragma unroll
        for (int ni = 0; ni < 4; ++ni) {
            const int gm = m0 + wm + mi * 16 + q * 4;
            const int gn = n0 + wn + ni * 16 + lrow;
            #pragma unroll
            for (int r = 0; r < 4; ++r) {
                if (z == 0) out[(size_t)(gm + r) * DIM + gn] = acc[mi][ni][r];
                else        ph[(size_t)(gm + r) * DIM + gn] = (_Float16)acc[mi][ni][r];
            }
        }
    }
}

// ---------------------------------------------------------------------------
// K5: out = (out + P1 + P2 + P3) / rowsum. rowsum: 64 partials/row.
// ---------------------------------------------------------------------------
__global__ void __launch_bounds__(128) add_inv_kernel(float* __restrict__ out,
                                                      const _Float16* __restrict__ P1,
                                                      const _Float16* __restrict__ P2,
                                                      const _Float16* __restrict__ P3,
                                                      const float* __restrict__ rowsum_part)
{
    const int row = blockIdx.x;
    const int t = threadIdx.x;
    float v = rowsum_part[(size_t)row * 64 + (t & 63)];
    v += __shfl_xor(v, 32, 64);
    v += __shfl_xor(v, 16, 64);
    v += __shfl_xor(v, 8, 64);
    v += __shfl_xor(v, 4, 64);
    v += __shfl_xor(v, 2, 64);
    v += __shfl_xor(v, 1, 64);
    const float inv = 1.0f / v;

    size_t i = (size_t)row * DIM + (size_t)t * 8;
    #pragma unroll
    for (int h = 0; h < 2; ++h) {
        size_t ii = i + h * 4;
        float4 a = *(const float4*)(out + ii);
        half4v b1 = *(const half4v*)(P1 + ii);
        half4v b2 = *(const half4v*)(P2 + ii);
        half4v b3 = *(const half4v*)(P3 + ii);
        a.x = (a.x + (float)b1[0] + (float)b2[0] + (float)b3[0]) * inv;
        a.y = (a.y + (float)b1[1] + (float)b2[1] + (float)b3[1]) * inv;
        a.z = (a.z + (float)b1[2] + (float)b2[2] + (float)b3[2]) * inv;
        a.w = (a.w + (float)b1[3] + (float)b2[3] + (float)b3[3]) * inv;
        *(float4*)(out + ii) = a;
    }
}

// ---------------------------------------------------------------------------
// launch
// ---------------------------------------------------------------------------
extern "C" void kernel_launch(void* const* d_in, const int* in_sizes, int n_in,
                              void* d_out, int out_size, void* d_ws, size_t ws_size,
                              hipStream_t stream)
{
    const float* x  = (const float*)d_in[0];
    const float* Wq = (const float*)d_in[1];
    const float* Wk = (const float*)d_in[2];
    const float* Wv = (const float*)d_in[3];
    const float* bq = (const float*)d_in[4];
    const float* bk = (const float*)d_in[5];
    const float* bv = (const float*)d_in[6];
    float* out = (float*)d_out;
    char* ws = (char*)d_ws;

    // workspace layout (70 MB peak; R12 scheme):
    //   0..8    xh   (dead after QKV)      -> rowsum_part @0 (1 MB, S phase)
    //   8..14   Wt   (dead after QKV)      -> P1 @2..10 (PV phase)
    //  14..22   qh   (dead after S)        -> P2 @11..19
    //  22..30   kh   (dead after S)        -> P3 @20..28
    //  30..38   vt   (alive through PV)
    //  38..46   vt0  (dead after combine; P overwrites in S phase)
    //  46..54   vt1  (dead after combine; P overwrites in S phase)
    //  38..70   P    (written in S, after vt0/vt1 dead)
    _Float16* xh  = (_Float16*)(ws);
    _Float16* Wt  = (_Float16*)(ws + (8ull  << 20));
    _Float16* qh  = (_Float16*)(ws + (14ull << 20));
    _Float16* kh  = (_Float16*)(ws + (22ull << 20));
    _Float16* vt  = (_Float16*)(ws + (30ull << 20));
    _Float16* vt0 = (_Float16*)(ws + (38ull << 20));
    _Float16* vt1 = (_Float16*)(ws + (46ull << 20));
    _Float16* P   = (_Float16*)(ws + (38ull << 20));
    float* rowsum_part = (float*)(ws);
    _Float16* P1  = (_Float16*)(ws + (2ull  << 20));
    _Float16* P2  = (_Float16*)(ws + (11ull << 20));
    _Float16* P3  = (_Float16*)(ws + (20ull << 20));

    prep_kernel<<<dim3(3072), 128, 0, stream>>>(x, Wq, Wk, Wv, xh, Wt);
    qkv_kernel<<<dim3(512), 256, 0, stream>>>(xh, Wt, bq, bk, bv, qh, kh, vt0, vt1);
    combine_v<<<dim3(NTOK * DIM / (256 * 8)), 256, 0, stream>>>(vt0, vt1, vt);
    s_kernel<<<dim3(1024), 256, 0, stream>>>(qh, kh, P, rowsum_part);
    pv_kernel<<<dim3(1024), 256, 0, stream>>>(P, vt, out, P1, P2, P3);
    add_inv_kernel<<<dim3(NTOK), 128, 0, stream>>>(out, P1, P2, P3, rowsum_part);
}

// Round 8
// 229.193 us; speedup vs baseline: 1.0026x; 1.0026x over previous
//
#include <hip/hip_runtime.h>
#include <hip/hip_fp16.h>
#include <cstdint>
#include <cstddef>

// ---------------------------------------------------------------------------
// SelfAttentionV2: out = softmax((x Wq + bq)(x Wk + bk)^T / 32) (x Wv + bv)
// N=4096, D=1024. fp32 in/out, fp16 MFMA internal.
// R20: GEMM-core plateau accepted (~780 TF for K=1024 shapes; 7 core
//   variants all 44-54us). Attack the non-GEMM ~120us instead:
//   - pv: FULL-K (4096), grid 256 (32mt x 8nt, 128^2 m97 core, R19-verified,
//     72 VGPR). P1/P2/P3 partials DELETED.
//   - softmax divide fused into pv epilogue via tiny rowsum_inv kernel
//     (64 partials -> inv[4096], 16KB L2-resident). add_inv DELETED.
//   - s: reverted to R16 256^2 single-region core (best family, ~44.5us).
//   - prep/qkv/combine_v verbatim R12.
//   Kernel count 6 -> 6 (one is tiny); HBM traffic -~100MB.
// ---------------------------------------------------------------------------

#define NTOK 4096
#define DIM  1024

typedef _Float16 half8  __attribute__((ext_vector_type(8)));
typedef _Float16 half4v __attribute__((ext_vector_type(4)));
typedef float    floatx4 __attribute__((ext_vector_type(4)));

#define GLOBAL_AS __attribute__((address_space(1)))
#define LDS_AS    __attribute__((address_space(3)))

__device__ __forceinline__ void lds_load16(const _Float16* gsrc, _Float16* ldst) {
    __builtin_amdgcn_global_load_lds((GLOBAL_AS void*)gsrc, (LDS_AS void*)ldst, 16, 0, 0);
}

// ---------------------------------------------------------------------------
// WIDE 4-WAVE NT GEMM core (verbatim R4/R9/R11, verified) — used by qkv.
// ---------------------------------------------------------------------------
__device__ __forceinline__ void gemm_wide_core(const _Float16* __restrict__ A,
                                               const _Float16* __restrict__ B,
                                               int K, int lda, int ldb,
                                               int m0, int n0,
                                               _Float16* ldsA, _Float16* ldsB,
                                               floatx4 acc[4][8])
{
    const int t    = threadIdx.x;
    const int lane = t & 63;
    const int wid  = t >> 6;
    const int wm   = (wid >> 1) * 64;
    const int wn   = (wid & 1) * 128;
    const int lrow = lane & 15;
    const int q    = lane >> 4;
    const int xk   = lrow & 7;

    const _Float16* asrc[4]; _Float16* adst[4];
    const _Float16* bsrc[8]; _Float16* bdst[8];
    #pragma unroll
    for (int i = 0; i < 4; ++i) {
        const int p = t + 256 * i, row = p >> 3;
        const int col = ((p & 7) ^ (row & 7)) * 8;
        asrc[i] = A + (size_t)(m0 + row) * lda + col;
        adst[i] = ldsA + p * 8;
    }
    #pragma unroll
    for (int i = 0; i < 8; ++i) {
        const int p = t + 256 * i, row = p >> 3;
        const int col = ((p & 7) ^ (row & 7)) * 8;
        bsrc[i] = B + (size_t)(n0 + row) * ldb + col;
        bdst[i] = ldsB + p * 8;
    }

    const _Float16* fa = ldsA + (wm + lrow) * 64;
    const _Float16* fb = ldsB + (wn + lrow) * 64;

    for (int k0 = 0; k0 < K; k0 += 64) {
        #pragma unroll
        for (int i = 0; i < 4; ++i) lds_load16(asrc[i] + k0, adst[i]);
        #pragma unroll
        for (int i = 0; i < 8; ++i) lds_load16(bsrc[i] + k0, bdst[i]);
        __syncthreads();

        #pragma unroll
        for (int s = 0; s < 2; ++s) {
            const int co = (((s * 4 + q) ^ xk) * 8);
            half8 af[4], bf[8];
            #pragma unroll
            for (int i = 0; i < 4; ++i) af[i] = *(const half8*)(fa + i * 1024 + co);
            #pragma unroll
            for (int i = 0; i < 8; ++i) bf[i] = *(const half8*)(fb + i * 1024 + co);
            #pragma unroll
            for (int ni = 0; ni < 8; ++ni)
                #pragma unroll
                for (int mi = 0; mi < 4; ++mi)
                    acc[mi][ni] = __builtin_amdgcn_mfma_f32_16x16x32_f16(
                        af[mi], bf[ni], acc[mi][ni], 0, 0, 0);
        }
        __syncthreads();
    }
}

// ---------------------------------------------------------------------------
// 256x256-tile 8-wave NT GEMM core v3 (verbatim R16) — used by s.
// ---------------------------------------------------------------------------
__device__ __forceinline__ void gemm256_core(const _Float16* __restrict__ A,
                                             const _Float16* __restrict__ B,
                                             int ktiles, int lda, int ldb,
                                             int m0, int n0,
                                             _Float16* ldsA, _Float16* ldsB,
                                             floatx4 acc[8][4])
{
    const int t    = threadIdx.x;        // 0..511
    const int lane = t & 63;
    const int wr   = (t >> 6) >> 2;      // 0..1
    const int wc   = (t >> 6) & 3;       // 0..3
    const int lrow = lane & 15;
    const int q    = lane >> 4;
    const int xk   = lrow & 7;

    const _Float16* asrc[4]; _Float16* adst[4];
    const _Float16* bsrc[4]; _Float16* bdst[4];
    #pragma unroll
    for (int i = 0; i < 4; ++i) {
        const int p = t + 512 * i, row = p >> 3, c8 = p & 7;
        const int col = (c8 ^ (row & 7)) * 8;
        asrc[i] = A + (size_t)(m0 + row) * lda + col;
        adst[i] = ldsA + row * 64 + c8 * 8;
        bsrc[i] = B + (size_t)(n0 + row) * ldb + col;
        bdst[i] = ldsB + row * 64 + c8 * 8;
    }

    const int faoff = (wr * 128 + lrow) * 64;
    const int fboff = (wc * 64 + lrow) * 64;

#define STAGE(T_) do { const size_t ko_ = (size_t)(T_) * 64; \
        const int bo_ = ((T_) & 1) * 16384; \
        _Pragma("unroll") \
        for (int i_ = 0; i_ < 4; ++i_) { \
            lds_load16(asrc[i_] + ko_, adst[i_] + bo_); \
            lds_load16(bsrc[i_] + ko_, bdst[i_] + bo_); } } while (0)

    STAGE(0);
    asm volatile("s_waitcnt vmcnt(0)" ::: "memory");
    __builtin_amdgcn_s_barrier();

    for (int T = 0; T < ktiles; ++T) {
        if (T + 1 < ktiles) STAGE(T + 1);

        const _Float16* fa = ldsA + (T & 1) * 16384 + faoff;
        const _Float16* fb = ldsB + (T & 1) * 16384 + fboff;
        #pragma unroll
        for (int s = 0; s < 2; ++s) {
            const int co = (((s * 4 + q) ^ xk) * 8);
            half8 af[8], bf[4];
            #pragma unroll
            for (int mi = 0; mi < 8; ++mi) af[mi] = *(const half8*)(fa + mi * 1024 + co);
            #pragma unroll
            for (int ni = 0; ni < 4; ++ni) bf[ni] = *(const half8*)(fb + ni * 1024 + co);
            #pragma unroll
            for (int ni = 0; ni < 4; ++ni)
                #pragma unroll
                for (int mi = 0; mi < 8; ++mi)
                    acc[mi][ni] = __builtin_amdgcn_mfma_f32_16x16x32_f16(
                        af[mi], bf[ni], acc[mi][ni], 0, 0, 0);
        }

        if (T + 1 < ktiles) {
            asm volatile("s_waitcnt vmcnt(0)" ::: "memory");
        }
        __builtin_amdgcn_s_barrier();
    }
#undef STAGE
}

// ---------------------------------------------------------------------------
// m97-blueprint core (verbatim R19, verified): 128x128 tile, 4 waves x 64x64,
// acc[4][4], BK=64 single-buffered, 2-barrier loop — used by pv (full-K).
// ---------------------------------------------------------------------------
__device__ __forceinline__ void gemm128_core(const _Float16* __restrict__ A,
                                             const _Float16* __restrict__ B,
                                             int K, int lda, int ldb,
                                             int m0, int n0,
                                             _Float16* ldsA, _Float16* ldsB,
                                             floatx4 acc[4][4])
{
    const int t    = threadIdx.x;        // 0..255
    const int lane = t & 63;
    const int wid  = t >> 6;             // 0..3
    const int wm   = (wid >> 1) * 64;
    const int wn   = (wid & 1) * 64;
    const int lrow = lane & 15;
    const int q    = lane >> 4;
    const int xk   = lrow & 7;

    const _Float16* asrc[4]; _Float16* adst[4];
    const _Float16* bsrc[4]; _Float16* bdst[4];
    #pragma unroll
    for (int i = 0; i < 4; ++i) {
        const int p = t + 256 * i, row = p >> 3, c8 = p & 7;
        const int col = (c8 ^ (row & 7)) * 8;
        asrc[i] = A + (size_t)(m0 + row) * lda + col;
        adst[i] = ldsA + row * 64 + c8 * 8;
        bsrc[i] = B + (size_t)(n0 + row) * ldb + col;
        bdst[i] = ldsB + row * 64 + c8 * 8;
    }

    const _Float16* fa = ldsA + (wm + lrow) * 64;
    const _Float16* fb = ldsB + (wn + lrow) * 64;

    for (int k0 = 0; k0 < K; k0 += 64) {
        #pragma unroll
        for (int i = 0; i < 4; ++i) {
            lds_load16(asrc[i] + k0, adst[i]);
            lds_load16(bsrc[i] + k0, bdst[i]);
        }
        __syncthreads();

        #pragma unroll
        for (int s = 0; s < 2; ++s) {
            const int co = (((s * 4 + q) ^ xk) * 8);
            half8 af[4], bf[4];
            #pragma unroll
            for (int i = 0; i < 4; ++i) af[i] = *(const half8*)(fa + i * 1024 + co);
            #pragma unroll
            for (int i = 0; i < 4; ++i) bf[i] = *(const half8*)(fb + i * 1024 + co);
            #pragma unroll
            for (int ni = 0; ni < 4; ++ni)
                #pragma unroll
                for (int mi = 0; mi < 4; ++mi)
                    acc[mi][ni] = __builtin_amdgcn_mfma_f32_16x16x32_f16(
                        af[mi], bf[ni], acc[mi][ni], 0, 0, 0);
        }
        __syncthreads();
    }
}

// ---------------------------------------------------------------------------
// K0: prep (verbatim R9 body, grid 3072).
// ---------------------------------------------------------------------------
__global__ void __launch_bounds__(128) prep_kernel(const float* __restrict__ x,
                                                   const float* __restrict__ W0,
                                                   const float* __restrict__ W1,
                                                   const float* __restrict__ W2,
                                                   _Float16* __restrict__ xh,
                                                   _Float16* __restrict__ Wt)
{
    __shared__ float tile[32 * 33];
    const int t = threadIdx.x;
    const int G = gridDim.x;

    for (size_t idx = (size_t)blockIdx.x * 128 + t; idx < (size_t)NTOK * DIM / 4;
         idx += (size_t)G * 128) {
        size_t i = idx * 4;
        float4 v = *(const float4*)(x + i);
        half4v h;
        h[0] = (_Float16)v.x; h[1] = (_Float16)v.y;
        h[2] = (_Float16)v.z; h[3] = (_Float16)v.w;
        *(half4v*)(xh + i) = h;
    }

    const int tx = t & 31, ty = t >> 5;   // ty in [0,4)
    for (int w = blockIdx.x; w < 3072; w += G) {
        const int z = w >> 10, r = w & 1023;
        const int nb = (r & 31) * 32, kb = (r >> 5) * 32;
        const float* W = (z == 0) ? W0 : (z == 1) ? W1 : W2;
        _Float16* outw = Wt + (size_t)z * DIM * DIM;
        #pragma unroll
        for (int i = 0; i < 32; i += 4)
            tile[(ty + i) * 33 + tx] = W[(size_t)(kb + ty + i) * DIM + nb + tx];
        __syncthreads();
        #pragma unroll
        for (int i = 0; i < 32; i += 4)
            outw[(size_t)(nb + ty + i) * DIM + kb + tx] =
                (_Float16)tile[tx * 33 + ty + i];
        __syncthreads();
    }
}

// ---------------------------------------------------------------------------
// K1: QKV mixed-K wide grid (verbatim R9/R12, verified; 512 blocks = 2/CU).
// ---------------------------------------------------------------------------
__global__ void __launch_bounds__(256, 2)
qkv_kernel(const _Float16* __restrict__ xh,
           const _Float16* __restrict__ Wt,
           const float* __restrict__ bq,
           const float* __restrict__ bk,
           const float* __restrict__ bv,
           _Float16* __restrict__ qh,
           _Float16* __restrict__ kh,
           _Float16* __restrict__ vt0,
           _Float16* __restrict__ vt1)
{
    __shared__ _Float16 ldsA[128 * 64];
    __shared__ _Float16 ldsB[256 * 64];

    const int b = blockIdx.x;

    const _Float16* A; const _Float16* B;
    const float* bias; _Float16* outm;
    int m0, n0, ldc, K, kstart; bool bias_by_row, do_bias;

    if (b < 256) {
        const int z = b >> 7;            // 0:q 1:k
        const int g = b & 127;
        const int xcd = g & 7;
        const int j   = g >> 3;          // 0..15
        const int mt  = xcd * 4 + (j & 3);   // 32 m-tiles
        const int nt  = j >> 2;              // 4 n-tiles of 256
        m0 = mt * 128; n0 = nt * 256; ldc = DIM;
        K = DIM; kstart = 0; bias_by_row = false; do_bias = true;
        A = xh;
        B = (z == 0) ? Wt : Wt + DIM * DIM;
        bias = (z == 0) ? bq : bk;
        outm = (z == 0) ? qh : kh;
    } else {
        const int h = (b - 256) >> 7;    // k-half 0/1
        const int g = b & 127;
        const int xcd = g & 7;
        const int j   = g >> 3;          // 0..15
        m0 = xcd * 128;                  // 8 m-tiles (d-dim)
        n0 = j * 256;                    // 16 n-tiles (tokens)
        ldc = NTOK;
        K = DIM / 2; kstart = h * (DIM / 2);
        bias_by_row = true; do_bias = (h == 0);
        A = Wt + 2 * DIM * DIM; B = xh; bias = bv;
        outm = (h == 0) ? vt0 : vt1;
    }

    floatx4 acc[4][8];
    #pragma unroll
    for (int mi = 0; mi < 4; ++mi)
        #pragma unroll
        for (int ni = 0; ni < 8; ++ni)
            #pragma unroll
            for (int r = 0; r < 4; ++r) acc[mi][ni][r] = 0.0f;

    gemm_wide_core(A + kstart, B + kstart, K, DIM, DIM, m0, n0, ldsA, ldsB, acc);

    const int lane = threadIdx.x & 63;
    const int wid  = threadIdx.x >> 6;
    const int wm   = (wid >> 1) * 64;
    const int wn   = (wid & 1) * 128;
    const int lrow = lane & 15;
    const int q    = lane >> 4;
    #pragma unroll
    for (int mi = 0; mi < 4; ++mi) {
        #pragma unroll
        for (int ni = 0; ni < 8; ++ni) {
            const int gm = m0 + wm + mi * 16 + q * 4;
            const int gn = n0 + wn + ni * 16 + lrow;
            const float bcol = (!do_bias || bias_by_row) ? 0.0f : bias[gn];
            #pragma unroll
            for (int r = 0; r < 4; ++r) {
                float bb = do_bias ? (bias_by_row ? bias[gm + r] : bcol) : 0.0f;
                outm[(size_t)(gm + r) * ldc + gn] = (_Float16)(acc[mi][ni][r] + bb);
            }
        }
    }
}

// ---------------------------------------------------------------------------
// K2: combine v partials: vt = vt0 + vt1 (verbatim R9).
// ---------------------------------------------------------------------------
__global__ void __launch_bounds__(256) combine_v(const _Float16* __restrict__ vt0,
                                                 const _Float16* __restrict__ vt1,
                                                 _Float16* __restrict__ vt)
{
    size_t i = ((size_t)blockIdx.x * 256 + threadIdx.x) * 8;
    half8 a = *(const half8*)(vt0 + i);
    half8 b = *(const half8*)(vt1 + i);
    half8 o;
    #pragma unroll
    for (int k = 0; k < 8; ++k) o[k] = (_Float16)((float)a[k] + (float)b[k]);
    *(half8*)(vt + i) = o;
}

// ---------------------------------------------------------------------------
// K3: S-GEMM + fused exp + partial rowsums — R16 256x256 core.
// grid 256 (16mt x 16ct), XCD-banded, 512 thr.
// rowsum partials: 64 per row = 16 ct x 4 waves(wc).
// ---------------------------------------------------------------------------
__global__ void __launch_bounds__(512) s_kernel(const _Float16* __restrict__ qh,
                                                const _Float16* __restrict__ kh,
                                                _Float16* __restrict__ P,
                                                float* __restrict__ rowsum_part)
{
    __shared__ _Float16 ldsA[2 * 256 * 64];   // 64 KiB
    __shared__ _Float16 ldsB[2 * 256 * 64];   // 64 KiB

    const int b   = blockIdx.x;
    const int xcd = b & 7;
    const int j   = b >> 3;              // 0..31
    const int mt  = xcd * 2 + (j & 1);   // 16 m-tiles of 256
    const int ct  = j >> 1;              // 16 n-tiles of 256
    const int m0  = mt * 256;
    const int n0  = ct * 256;

    floatx4 acc[8][4];
    #pragma unroll
    for (int mi = 0; mi < 8; ++mi)
        #pragma unroll
        for (int ni = 0; ni < 4; ++ni)
            #pragma unroll
            for (int r = 0; r < 4; ++r) acc[mi][ni][r] = 0.0f;

    gemm256_core(qh, kh, DIM / 64, DIM, DIM, m0, n0, ldsA, ldsB, acc);

    const int lane = threadIdx.x & 63;
    const int wr   = (threadIdx.x >> 6) >> 2;
    const int wc   = (threadIdx.x >> 6) & 3;
    const int lrow = lane & 15;
    const int q    = lane >> 4;

    #pragma unroll
    for (int mi = 0; mi < 8; ++mi) {
        #pragma unroll
        for (int r = 0; r < 4; ++r) {
            const int gm = m0 + wr * 128 + mi * 16 + q * 4 + r;
            float rs = 0.0f;
            #pragma unroll
            for (int ni = 0; ni < 4; ++ni) {
                const int gn = n0 + wc * 64 + ni * 16 + lrow;
                float e = __expf(acc[mi][ni][r] * 0.03125f - 8.0f);
                P[(size_t)gm * NTOK + gn] = (_Float16)e;
                rs += e;
            }
            rs += __shfl_xor(rs, 1, 64);
            rs += __shfl_xor(rs, 2, 64);
            rs += __shfl_xor(rs, 4, 64);
            rs += __shfl_xor(rs, 8, 64);
            if (lrow == 0) rowsum_part[(size_t)gm * 64 + ct * 4 + wc] = rs;
        }
    }
}

// ---------------------------------------------------------------------------
// K3b: rowsum finalize — inv[row] = 1 / sum64(rowsum_part[row]).
// grid 16 x 256 thr; one row per thread; float4 x16 contiguous reads.
// ---------------------------------------------------------------------------
__global__ void __launch_bounds__(256) rowsum_inv_kernel(
    const float* __restrict__ rowsum_part, float* __restrict__ inv)
{
    const int row = blockIdx.x * 256 + threadIdx.x;
    const float* p = rowsum_part + (size_t)row * 64;
    float s = 0.0f;
    #pragma unroll
    for (int i = 0; i < 16; ++i) {
        float4 v = *(const float4*)(p + i * 4);
        s += v.x + v.y + v.z + v.w;
    }
    inv[row] = 1.0f / s;
}

// ---------------------------------------------------------------------------
// K4: PV full-K + fused softmax divide. grid 256 (32mt x 8nt), XCD-banded.
// out[gm][gn] = (P[gm,:] . vt[gn,:]) * inv[gm], fp32.
// ---------------------------------------------------------------------------
__global__ void __launch_bounds__(256) pv_kernel(const _Float16* __restrict__ P,
                                                 const _Float16* __restrict__ vt,
                                                 const float* __restrict__ inv,
                                                 float* __restrict__ out)
{
    __shared__ _Float16 ldsA[128 * 64];
    __shared__ _Float16 ldsB[128 * 64];

    const int b   = blockIdx.x;
    const int xcd = b & 7;
    const int j   = b >> 3;              // 0..31
    const int mt  = xcd * 4 + (j & 3);   // 32 m-tiles of 128 (tokens)
    const int nt  = j >> 2;              // 8 n-tiles of 128 (dim)
    const int m0  = mt * 128;
    const int n0  = nt * 128;

    floatx4 acc[4][4];
    #pragma unroll
    for (int mi = 0; mi < 4; ++mi)
        #pragma unroll
        for (int ni = 0; ni < 4; ++ni)
            #pragma unroll
            for (int r = 0; r < 4; ++r) acc[mi][ni][r] = 0.0f;

    gemm128_core(P, vt, NTOK, NTOK, NTOK, m0, n0, ldsA, ldsB, acc);

    const int lane = threadIdx.x & 63;
    const int wid  = threadIdx.x >> 6;
    const int wm   = (wid >> 1) * 64;
    const int wn   = (wid & 1) * 64;
    const int lrow = lane & 15;
    const int q    = lane >> 4;

    #pragma unroll
    for (int mi = 0; mi < 4; ++mi) {
        const int gm = m0 + wm + mi * 16 + q * 4;
        float iv[4];
        #pragma unroll
        for (int r = 0; r < 4; ++r) iv[r] = inv[gm + r];
        #pragma unroll
        for (int ni = 0; ni < 4; ++ni) {
            const int gn = n0 + wn + ni * 16 + lrow;
            #pragma unroll
            for (int r = 0; r < 4; ++r)
                out[(size_t)(gm + r) * DIM + gn] = acc[mi][ni][r] * iv[r];
        }
    }
}

// ---------------------------------------------------------------------------
// launch
// ---------------------------------------------------------------------------
extern "C" void kernel_launch(void* const* d_in, const int* in_sizes, int n_in,
                              void* d_out, int out_size, void* d_ws, size_t ws_size,
                              hipStream_t stream)
{
    const float* x  = (const float*)d_in[0];
    const float* Wq = (const float*)d_in[1];
    const float* Wk = (const float*)d_in[2];
    const float* Wv = (const float*)d_in[3];
    const float* bq = (const float*)d_in[4];
    const float* bk = (const float*)d_in[5];
    const float* bv = (const float*)d_in[6];
    float* out = (float*)d_out;
    char* ws = (char*)d_ws;

    // workspace layout (70 MB peak):
    //   0..8    xh   (dead after QKV)      -> rowsum_part @0 (1 MB, S phase)
    //                                      -> inv @ 1.5MB (16 KB, PV phase)
    //   8..14   Wt   (dead after QKV)
    //  14..22   qh   (dead after S)
    //  22..30   kh   (dead after S)
    //  30..38   vt   (alive through PV)
    //  38..46   vt0  (dead after combine; P overwrites in S phase)
    //  46..54   vt1  (dead after combine; P overwrites in S phase)
    //  38..70   P    (written in S, after vt0/vt1 dead)
    _Float16* xh  = (_Float16*)(ws);
    _Float16* Wt  = (_Float16*)(ws + (8ull  << 20));
    _Float16* qh  = (_Float16*)(ws + (14ull << 20));
    _Float16* kh  = (_Float16*)(ws + (22ull << 20));
    _Float16* vt  = (_Float16*)(ws + (30ull << 20));
    _Float16* vt0 = (_Float16*)(ws + (38ull << 20));
    _Float16* vt1 = (_Float16*)(ws + (46ull << 20));
    _Float16* P   = (_Float16*)(ws + (38ull << 20));
    float* rowsum_part = (float*)(ws);
    float* inv    = (float*)(ws + (1536ull << 10));

    prep_kernel<<<dim3(3072), 128, 0, stream>>>(x, Wq, Wk, Wv, xh, Wt);
    qkv_kernel<<<dim3(512), 256, 0, stream>>>(xh, Wt, bq, bk, bv, qh, kh, vt0, vt1);
    combine_v<<<dim3(NTOK * DIM / (256 * 8)), 256, 0, stream>>>(vt0, vt1, vt);
    s_kernel<<<dim3(256), 512, 0, stream>>>(qh, kh, P, rowsum_part);
    rowsum_inv_kernel<<<dim3(16), 256, 0, stream>>>(rowsum_part, inv);
    pv_kernel<<<dim3(256), 256, 0, stream>>>(P, vt, inv, out);
}

// Round 9
// 217.268 us; speedup vs baseline: 1.0576x; 1.0549x over previous
//
#include <hip/hip_runtime.h>
#include <hip/hip_fp16.h>
#include <cstdint>
#include <cstddef>

// ---------------------------------------------------------------------------
// SelfAttentionV2: out = softmax((x Wq + bq)(x Wk + bk)^T / 32) (x Wv + bv)
// N=4096, D=1024. fp32 in/out, fp16 MFMA internal.
// R21: consolidation. R20's full-K pv regressed (256 blocks = 4 waves/CU,
//   occupancy 10%, 72us) -> split-K=4 restored. Revert to R16 champion
//   (209.4us) + one structural save: combine_v launch DELETED:
//   - qkv v-task h==1 writes vt directly (h==0 -> vt0, carries bias)
//   - s_kernel blocks run a tail after their epilogue: vt += vt0 over a
//     disjoint 16K-half slice per block (pv launches after s => complete).
//   Workspace relayout (65MB peak): qh 0-8, kh 8-16, vt 16-24, vt0 24-32,
//   P 32-64 (over dead xh@32-40/Wt@40-46), rowsum 64-65;
//   pv phase: P1@0 (qh dead), P2@8 (kh dead), P3@24 (vt0 dead).
//   s: R16 256^2 single-region core; pv: R16 v3 split-K=4; add_inv: R16.
// ---------------------------------------------------------------------------

#define NTOK 4096
#define DIM  1024

typedef _Float16 half8  __attribute__((ext_vector_type(8)));
typedef _Float16 half4v __attribute__((ext_vector_type(4)));
typedef float    floatx4 __attribute__((ext_vector_type(4)));

#define GLOBAL_AS __attribute__((address_space(1)))
#define LDS_AS    __attribute__((address_space(3)))

__device__ __forceinline__ void lds_load16(const _Float16* gsrc, _Float16* ldst) {
    __builtin_amdgcn_global_load_lds((GLOBAL_AS void*)gsrc, (LDS_AS void*)ldst, 16, 0, 0);
}

// ---------------------------------------------------------------------------
// WIDE 4-WAVE NT GEMM core (verbatim R4/R9/R11, verified) — used by qkv.
// ---------------------------------------------------------------------------
__device__ __forceinline__ void gemm_wide_core(const _Float16* __restrict__ A,
                                               const _Float16* __restrict__ B,
                                               int K, int lda, int ldb,
                                               int m0, int n0,
                                               _Float16* ldsA, _Float16* ldsB,
                                               floatx4 acc[4][8])
{
    const int t    = threadIdx.x;
    const int lane = t & 63;
    const int wid  = t >> 6;
    const int wm   = (wid >> 1) * 64;
    const int wn   = (wid & 1) * 128;
    const int lrow = lane & 15;
    const int q    = lane >> 4;
    const int xk   = lrow & 7;

    const _Float16* asrc[4]; _Float16* adst[4];
    const _Float16* bsrc[8]; _Float16* bdst[8];
    #pragma unroll
    for (int i = 0; i < 4; ++i) {
        const int p = t + 256 * i, row = p >> 3;
        const int col = ((p & 7) ^ (row & 7)) * 8;
        asrc[i] = A + (size_t)(m0 + row) * lda + col;
        adst[i] = ldsA + p * 8;
    }
    #pragma unroll
    for (int i = 0; i < 8; ++i) {
        const int p = t + 256 * i, row = p >> 3;
        const int col = ((p & 7) ^ (row & 7)) * 8;
        bsrc[i] = B + (size_t)(n0 + row) * ldb + col;
        bdst[i] = ldsB + p * 8;
    }

    const _Float16* fa = ldsA + (wm + lrow) * 64;
    const _Float16* fb = ldsB + (wn + lrow) * 64;

    for (int k0 = 0; k0 < K; k0 += 64) {
        #pragma unroll
        for (int i = 0; i < 4; ++i) lds_load16(asrc[i] + k0, adst[i]);
        #pragma unroll
        for (int i = 0; i < 8; ++i) lds_load16(bsrc[i] + k0, bdst[i]);
        __syncthreads();

        #pragma unroll
        for (int s = 0; s < 2; ++s) {
            const int co = (((s * 4 + q) ^ xk) * 8);
            half8 af[4], bf[8];
            #pragma unroll
            for (int i = 0; i < 4; ++i) af[i] = *(const half8*)(fa + i * 1024 + co);
            #pragma unroll
            for (int i = 0; i < 8; ++i) bf[i] = *(const half8*)(fb + i * 1024 + co);
            #pragma unroll
            for (int ni = 0; ni < 8; ++ni)
                #pragma unroll
                for (int mi = 0; mi < 4; ++mi)
                    acc[mi][ni] = __builtin_amdgcn_mfma_f32_16x16x32_f16(
                        af[mi], bf[ni], acc[mi][ni], 0, 0, 0);
        }
        __syncthreads();
    }
}

// ---------------------------------------------------------------------------
// 256x256-tile 8-wave NT GEMM core v3 (verbatim R16) — used by s and pv.
// ---------------------------------------------------------------------------
__device__ __forceinline__ void gemm256_core(const _Float16* __restrict__ A,
                                             const _Float16* __restrict__ B,
                                             int ktiles, int lda, int ldb,
                                             int m0, int n0,
                                             _Float16* ldsA, _Float16* ldsB,
                                             floatx4 acc[8][4])
{
    const int t    = threadIdx.x;        // 0..511
    const int lane = t & 63;
    const int wr   = (t >> 6) >> 2;      // 0..1
    const int wc   = (t >> 6) & 3;       // 0..3
    const int lrow = lane & 15;
    const int q    = lane >> 4;
    const int xk   = lrow & 7;

    const _Float16* asrc[4]; _Float16* adst[4];
    const _Float16* bsrc[4]; _Float16* bdst[4];
    #pragma unroll
    for (int i = 0; i < 4; ++i) {
        const int p = t + 512 * i, row = p >> 3, c8 = p & 7;
        const int col = (c8 ^ (row & 7)) * 8;
        asrc[i] = A + (size_t)(m0 + row) * lda + col;
        adst[i] = ldsA + row * 64 + c8 * 8;
        bsrc[i] = B + (size_t)(n0 + row) * ldb + col;
        bdst[i] = ldsB + row * 64 + c8 * 8;
    }

    const int faoff = (wr * 128 + lrow) * 64;
    const int fboff = (wc * 64 + lrow) * 64;

#define STAGE(T_) do { const size_t ko_ = (size_t)(T_) * 64; \
        const int bo_ = ((T_) & 1) * 16384; \
        _Pragma("unroll") \
        for (int i_ = 0; i_ < 4; ++i_) { \
            lds_load16(asrc[i_] + ko_, adst[i_] + bo_); \
            lds_load16(bsrc[i_] + ko_, bdst[i_] + bo_); } } while (0)

    STAGE(0);
    asm volatile("s_waitcnt vmcnt(0)" ::: "memory");
    __builtin_amdgcn_s_barrier();

    for (int T = 0; T < ktiles; ++T) {
        if (T + 1 < ktiles) STAGE(T + 1);

        const _Float16* fa = ldsA + (T & 1) * 16384 + faoff;
        const _Float16* fb = ldsB + (T & 1) * 16384 + fboff;
        #pragma unroll
        for (int s = 0; s < 2; ++s) {
            const int co = (((s * 4 + q) ^ xk) * 8);
            half8 af[8], bf[4];
            #pragma unroll
            for (int mi = 0; mi < 8; ++mi) af[mi] = *(const half8*)(fa + mi * 1024 + co);
            #pragma unroll
            for (int ni = 0; ni < 4; ++ni) bf[ni] = *(const half8*)(fb + ni * 1024 + co);
            #pragma unroll
            for (int ni = 0; ni < 4; ++ni)
                #pragma unroll
                for (int mi = 0; mi < 8; ++mi)
                    acc[mi][ni] = __builtin_amdgcn_mfma_f32_16x16x32_f16(
                        af[mi], bf[ni], acc[mi][ni], 0, 0, 0);
        }

        if (T + 1 < ktiles) {
            asm volatile("s_waitcnt vmcnt(0)" ::: "memory");
        }
        __builtin_amdgcn_s_barrier();
    }
#undef STAGE
}

// ---------------------------------------------------------------------------
// K0: prep (verbatim R9 body, grid 3072).
// ---------------------------------------------------------------------------
__global__ void __launch_bounds__(128) prep_kernel(const float* __restrict__ x,
                                                   const float* __restrict__ W0,
                                                   const float* __restrict__ W1,
                                                   const float* __restrict__ W2,
                                                   _Float16* __restrict__ xh,
                                                   _Float16* __restrict__ Wt)
{
    __shared__ float tile[32 * 33];
    const int t = threadIdx.x;
    const int G = gridDim.x;

    for (size_t idx = (size_t)blockIdx.x * 128 + t; idx < (size_t)NTOK * DIM / 4;
         idx += (size_t)G * 128) {
        size_t i = idx * 4;
        float4 v = *(const float4*)(x + i);
        half4v h;
        h[0] = (_Float16)v.x; h[1] = (_Float16)v.y;
        h[2] = (_Float16)v.z; h[3] = (_Float16)v.w;
        *(half4v*)(xh + i) = h;
    }

    const int tx = t & 31, ty = t >> 5;   // ty in [0,4)
    for (int w = blockIdx.x; w < 3072; w += G) {
        const int z = w >> 10, r = w & 1023;
        const int nb = (r & 31) * 32, kb = (r >> 5) * 32;
        const float* W = (z == 0) ? W0 : (z == 1) ? W1 : W2;
        _Float16* outw = Wt + (size_t)z * DIM * DIM;
        #pragma unroll
        for (int i = 0; i < 32; i += 4)
            tile[(ty + i) * 33 + tx] = W[(size_t)(kb + ty + i) * DIM + nb + tx];
        __syncthreads();
        #pragma unroll
        for (int i = 0; i < 32; i += 4)
            outw[(size_t)(nb + ty + i) * DIM + kb + tx] =
                (_Float16)tile[tx * 33 + ty + i];
        __syncthreads();
    }
}

// ---------------------------------------------------------------------------
// K1: QKV mixed-K wide grid (R12 structure; v h==0 -> vt0 (with bias),
// v h==1 -> vt DIRECTLY; s_kernel's tail computes vt += vt0).
// ---------------------------------------------------------------------------
__global__ void __launch_bounds__(256, 2)
qkv_kernel(const _Float16* __restrict__ xh,
           const _Float16* __restrict__ Wt,
           const float* __restrict__ bq,
           const float* __restrict__ bk,
           const float* __restrict__ bv,
           _Float16* __restrict__ qh,
           _Float16* __restrict__ kh,
           _Float16* __restrict__ vt0,
           _Float16* __restrict__ vt)
{
    __shared__ _Float16 ldsA[128 * 64];
    __shared__ _Float16 ldsB[256 * 64];

    const int b = blockIdx.x;

    const _Float16* A; const _Float16* B;
    const float* bias; _Float16* outm;
    int m0, n0, ldc, K, kstart; bool bias_by_row, do_bias;

    if (b < 256) {
        const int z = b >> 7;            // 0:q 1:k
        const int g = b & 127;
        const int xcd = g & 7;
        const int j   = g >> 3;          // 0..15
        const int mt  = xcd * 4 + (j & 3);   // 32 m-tiles
        const int nt  = j >> 2;              // 4 n-tiles of 256
        m0 = mt * 128; n0 = nt * 256; ldc = DIM;
        K = DIM; kstart = 0; bias_by_row = false; do_bias = true;
        A = xh;
        B = (z == 0) ? Wt : Wt + DIM * DIM;
        bias = (z == 0) ? bq : bk;
        outm = (z == 0) ? qh : kh;
    } else {
        const int h = (b - 256) >> 7;    // k-half 0/1
        const int g = b & 127;
        const int xcd = g & 7;
        const int j   = g >> 3;          // 0..15
        m0 = xcd * 128;                  // 8 m-tiles (d-dim)
        n0 = j * 256;                    // 16 n-tiles (tokens)
        ldc = NTOK;
        K = DIM / 2; kstart = h * (DIM / 2);
        bias_by_row = true; do_bias = (h == 0);
        A = Wt + 2 * DIM * DIM; B = xh; bias = bv;
        outm = (h == 0) ? vt0 : vt;
    }

    floatx4 acc[4][8];
    #pragma unroll
    for (int mi = 0; mi < 4; ++mi)
        #pragma unroll
        for (int ni = 0; ni < 8; ++ni)
            #pragma unroll
            for (int r = 0; r < 4; ++r) acc[mi][ni][r] = 0.0f;

    gemm_wide_core(A + kstart, B + kstart, K, DIM, DIM, m0, n0, ldsA, ldsB, acc);

    const int lane = threadIdx.x & 63;
    const int wid  = threadIdx.x >> 6;
    const int wm   = (wid >> 1) * 64;
    const int wn   = (wid & 1) * 128;
    const int lrow = lane & 15;
    const int q    = lane >> 4;
    #pragma unroll
    for (int mi = 0; mi < 4; ++mi) {
        #pragma unroll
        for (int ni = 0; ni < 8; ++ni) {
            const int gm = m0 + wm + mi * 16 + q * 4;
            const int gn = n0 + wn + ni * 16 + lrow;
            const float bcol = (!do_bias || bias_by_row) ? 0.0f : bias[gn];
            #pragma unroll
            for (int r = 0; r < 4; ++r) {
                float bb = do_bias ? (bias_by_row ? bias[gm + r] : bcol) : 0.0f;
                outm[(size_t)(gm + r) * ldc + gn] = (_Float16)(acc[mi][ni][r] + bb);
            }
        }
    }
}

// ---------------------------------------------------------------------------
// K3: S-GEMM + fused exp + partial rowsums + per-block combine tail
// (vt += vt0, 16384-half slice per block). grid 256, 512 thr.
// rowsum partials: 64 per row = 16 ct x 4 waves(wc).
// ---------------------------------------------------------------------------
__global__ void __launch_bounds__(512) s_kernel(const _Float16* __restrict__ qh,
                                                const _Float16* __restrict__ kh,
                                                _Float16* __restrict__ P,
                                                float* __restrict__ rowsum_part,
                                                _Float16* __restrict__ vt,
                                                const _Float16* __restrict__ vt0)
{
    __shared__ _Float16 ldsA[2 * 256 * 64];   // 64 KiB
    __shared__ _Float16 ldsB[2 * 256 * 64];   // 64 KiB

    const int b   = blockIdx.x;
    const int xcd = b & 7;
    const int j   = b >> 3;              // 0..31
    const int mt  = xcd * 2 + (j & 1);   // 16 m-tiles of 256
    const int ct  = j >> 1;              // 16 n-tiles of 256
    const int m0  = mt * 256;
    const int n0  = ct * 256;

    floatx4 acc[8][4];
    #pragma unroll
    for (int mi = 0; mi < 8; ++mi)
        #pragma unroll
        for (int ni = 0; ni < 4; ++ni)
            #pragma unroll
            for (int r = 0; r < 4; ++r) acc[mi][ni][r] = 0.0f;

    gemm256_core(qh, kh, DIM / 64, DIM, DIM, m0, n0, ldsA, ldsB, acc);

    const int lane = threadIdx.x & 63;
    const int wr   = (threadIdx.x >> 6) >> 2;
    const int wc   = (threadIdx.x >> 6) & 3;
    const int lrow = lane & 15;
    const int q    = lane >> 4;

    #pragma unroll
    for (int mi = 0; mi < 8; ++mi) {
        #pragma unroll
        for (int r = 0; r < 4; ++r) {
            const int gm = m0 + wr * 128 + mi * 16 + q * 4 + r;
            float rs = 0.0f;
            #pragma unroll
            for (int ni = 0; ni < 4; ++ni) {
                const int gn = n0 + wc * 64 + ni * 16 + lrow;
                float e = __expf(acc[mi][ni][r] * 0.03125f - 8.0f);
                P[(size_t)gm * NTOK + gn] = (_Float16)e;
                rs += e;
            }
            rs += __shfl_xor(rs, 1, 64);
            rs += __shfl_xor(rs, 2, 64);
            rs += __shfl_xor(rs, 4, 64);
            rs += __shfl_xor(rs, 8, 64);
            if (lrow == 0) rowsum_part[(size_t)gm * 64 + ct * 4 + wc] = rs;
        }
    }

    // combine tail: vt += vt0 over this block's disjoint slice.
    // 1024*4096 halfs / 256 blocks = 16384/block = 32/thread = 4 x half8.
    const size_t cbase = (size_t)b * 16384 + (size_t)threadIdx.x * 32;
    #pragma unroll
    for (int i = 0; i < 4; ++i) {
        const size_t idx = cbase + (size_t)i * 8;
        half8 a = *(const half8*)(vt + idx);
        half8 c = *(const half8*)(vt0 + idx);
        half8 o;
        #pragma unroll
        for (int k = 0; k < 8; ++k) o[k] = (_Float16)((float)a[k] + (float)c[k]);
        *(half8*)(vt + idx) = o;
    }
}

// ---------------------------------------------------------------------------
// K4: PV split-K=4 — R16 v3 core verbatim. grid 256 (4z x 16mt x 4ct).
// z=0 -> fp32 out raw; z=1..3 -> fp16 partials.
// ---------------------------------------------------------------------------
__global__ void __launch_bounds__(512) pv_kernel(const _Float16* __restrict__ P,
                                                 const _Float16* __restrict__ vt,
                                                 float* __restrict__ out,
                                                 _Float16* __restrict__ P1,
                                                 _Float16* __restrict__ P2,
                                                 _Float16* __restrict__ P3)
{
    __shared__ _Float16 ldsA[2 * 256 * 64];
    __shared__ _Float16 ldsB[2 * 256 * 64];

    const int b   = blockIdx.x;
    const int z   = b >> 6;              // 0..3
    const int g   = b & 63;
    const int xcd = g & 7;
    const int j   = g >> 3;              // 0..7
    const int mt  = xcd * 2 + (j & 1);   // 16 m-tiles of 256 (tokens)
    const int ct  = j >> 1;              // 4 n-tiles of 256 (dim)
    const int m0  = mt * 256;
    const int n0  = ct * 256;
    const int kstart = z * (NTOK / 4);

    floatx4 acc[8][4];
    #pragma unroll
    for (int mi = 0; mi < 8; ++mi)
        #pragma unroll
        for (int ni = 0; ni < 4; ++ni)
            #pragma unroll
            for (int r = 0; r < 4; ++r) acc[mi][ni][r] = 0.0f;

    gemm256_core(P + kstart, vt + kstart, (NTOK / 4) / 64, NTOK, NTOK, m0, n0,
                 ldsA, ldsB, acc);

    const int lane = threadIdx.x & 63;
    const int wr   = (threadIdx.x >> 6) >> 2;
    const int wc   = (threadIdx.x >> 6) & 3;
    const int lrow = lane & 15;
    const int q    = lane >> 4;

    _Float16* ph = (z == 1) ? P1 : (z == 2) ? P2 : P3;
    #pragma unroll
    for (int mi = 0; mi < 8; ++mi) {
        #pragma unroll
        for (int ni = 0; ni < 4; ++ni) {
            const int gm = m0 + wr * 128 + mi * 16 + q * 4;
            const int gn = n0 + wc * 64 + ni * 16 + lrow;
            #pragma unroll
            for (int r = 0; r < 4; ++r) {
                if (z == 0) out[(size_t)(gm + r) * DIM + gn] = acc[mi][ni][r];
                else        ph[(size_t)(gm + r) * DIM + gn] = (_Float16)acc[mi][ni][r];
            }
        }
    }
}

// ---------------------------------------------------------------------------
// K5: out = (out + P1 + P2 + P3) / rowsum. rowsum: 64 partials/row.
// ---------------------------------------------------------------------------
__global__ void __launch_bounds__(128) add_inv_kernel(float* __restrict__ out,
                                                      const _Float16* __restrict__ P1,
                                                      const _Float16* __restrict__ P2,
                                                      const _Float16* __restrict__ P3,
                                                      const float* __restrict__ rowsum_part)
{
    const int row = blockIdx.x;
    const int t = threadIdx.x;
    float v = rowsum_part[(size_t)row * 64 + (t & 63)];
    v += __shfl_xor(v, 32, 64);
    v += __shfl_xor(v, 16, 64);
    v += __shfl_xor(v, 8, 64);
    v += __shfl_xor(v, 4, 64);
    v += __shfl_xor(v, 2, 64);
    v += __shfl_xor(v, 1, 64);
    const float inv = 1.0f / v;

    size_t i = (size_t)row * DIM + (size_t)t * 8;
    #pragma unroll
    for (int h = 0; h < 2; ++h) {
        size_t ii = i + h * 4;
        float4 a = *(const float4*)(out + ii);
        half4v b1 = *(const half4v*)(P1 + ii);
        half4v b2 = *(const half4v*)(P2 + ii);
        half4v b3 = *(const half4v*)(P3 + ii);
        a.x = (a.x + (float)b1[0] + (float)b2[0] + (float)b3[0]) * inv;
        a.y = (a.y + (float)b1[1] + (float)b2[1] + (float)b3[1]) * inv;
        a.z = (a.z + (float)b1[2] + (float)b2[2] + (float)b3[2]) * inv;
        a.w = (a.w + (float)b1[3] + (float)b2[3] + (float)b3[3]) * inv;
        *(float4*)(out + ii) = a;
    }
}

// ---------------------------------------------------------------------------
// launch
// ---------------------------------------------------------------------------
extern "C" void kernel_launch(void* const* d_in, const int* in_sizes, int n_in,
                              void* d_out, int out_size, void* d_ws, size_t ws_size,
                              hipStream_t stream)
{
    const float* x  = (const float*)d_in[0];
    const float* Wq = (const float*)d_in[1];
    const float* Wk = (const float*)d_in[2];
    const float* Wv = (const float*)d_in[3];
    const float* bq = (const float*)d_in[4];
    const float* bk = (const float*)d_in[5];
    const float* bv = (const float*)d_in[6];
    float* out = (float*)d_out;
    char* ws = (char*)d_ws;

    // workspace layout (65 MB peak):
    //   0..8    qh   (written qkv, read s; dead after s)   -> P1 (pv phase)
    //   8..16   kh   (written qkv, read s; dead after s)   -> P2 (pv phase)
    //  16..24   vt   (qkv h==1 writes; s-tail adds vt0; read pv)
    //  24..32   vt0  (qkv h==0 writes w/ bias; dead after s-tail) -> P3
    //  32..40   xh   (prep->qkv; dead after qkv)  \ P @32..64 (s phase)
    //  40..46   Wt   (prep->qkv; dead after qkv)  /
    //  64..65   rowsum_part (s phase; read add_inv)
    _Float16* qh  = (_Float16*)(ws);
    _Float16* kh  = (_Float16*)(ws + (8ull  << 20));
    _Float16* vt  = (_Float16*)(ws + (16ull << 20));
    _Float16* vt0 = (_Float16*)(ws + (24ull << 20));
    _Float16* xh  = (_Float16*)(ws + (32ull << 20));
    _Float16* Wt  = (_Float16*)(ws + (40ull << 20));
    _Float16* P   = (_Float16*)(ws + (32ull << 20));
    float* rowsum_part = (float*)(ws + (64ull << 20));
    _Float16* P1  = (_Float16*)(ws);
    _Float16* P2  = (_Float16*)(ws + (8ull  << 20));
    _Float16* P3  = (_Float16*)(ws + (24ull << 20));

    prep_kernel<<<dim3(3072), 128, 0, stream>>>(x, Wq, Wk, Wv, xh, Wt);
    qkv_kernel<<<dim3(512), 256, 0, stream>>>(xh, Wt, bq, bk, bv, qh, kh, vt0, vt);
    s_kernel<<<dim3(256), 512, 0, stream>>>(qh, kh, P, rowsum_part, vt, vt0);
    pv_kernel<<<dim3(256), 512, 0, stream>>>(P, vt, out, P1, P2, P3);
    add_inv_kernel<<<dim3(NTOK), 128, 0, stream>>>(out, P1, P2, P3, rowsum_part);
}

// Round 10
// 216.250 us; speedup vs baseline: 1.0626x; 1.0047x over previous
//
#include <hip/hip_runtime.h>
#include <hip/hip_fp16.h>
#include <cstdint>
#include <cstddef>

// ---------------------------------------------------------------------------
// SelfAttentionV2: out = softmax((x Wq + bq)(x Wk + bk)^T / 32) (x Wv + bv)
// N=4096, D=1024. fp32 in/out, fp16 MFMA internal.
// R22: exact R16 champion config (209.4us) — kernels, grids, and the 70MB
//   workspace layout restored verbatim (R21's relayout cost ~8us) — with
//   ONE change: prep rewritten for bandwidth:
//   - 256-thr blocks, grid 2048
//   - phase 1: x cvt as 32B reads -> 16B half8 stores, exact cover, no loop
//   - phase 2: W transpose in 64x64 tiles (768 tasks), LDS [64][72] fp16
//     (rows 144B = 16B-aligned), 256B-coalesced loads, 32B/lane row stores.
//   Accounting probe: if prep was the hidden cost (qkv+prep ~ 105us vs
//   ~40 ideal), total drops toward ~195; if not, qkv is next target.
// ---------------------------------------------------------------------------

#define NTOK 4096
#define DIM  1024

typedef _Float16 half8  __attribute__((ext_vector_type(8)));
typedef _Float16 half4v __attribute__((ext_vector_type(4)));
typedef float    floatx4 __attribute__((ext_vector_type(4)));

#define GLOBAL_AS __attribute__((address_space(1)))
#define LDS_AS    __attribute__((address_space(3)))

__device__ __forceinline__ void lds_load16(const _Float16* gsrc, _Float16* ldst) {
    __builtin_amdgcn_global_load_lds((GLOBAL_AS void*)gsrc, (LDS_AS void*)ldst, 16, 0, 0);
}

// ---------------------------------------------------------------------------
// WIDE 4-WAVE NT GEMM core (verbatim R4/R9/R11, verified) — used by qkv.
// ---------------------------------------------------------------------------
__device__ __forceinline__ void gemm_wide_core(const _Float16* __restrict__ A,
                                               const _Float16* __restrict__ B,
                                               int K, int lda, int ldb,
                                               int m0, int n0,
                                               _Float16* ldsA, _Float16* ldsB,
                                               floatx4 acc[4][8])
{
    const int t    = threadIdx.x;
    const int lane = t & 63;
    const int wid  = t >> 6;
    const int wm   = (wid >> 1) * 64;
    const int wn   = (wid & 1) * 128;
    const int lrow = lane & 15;
    const int q    = lane >> 4;
    const int xk   = lrow & 7;

    const _Float16* asrc[4]; _Float16* adst[4];
    const _Float16* bsrc[8]; _Float16* bdst[8];
    #pragma unroll
    for (int i = 0; i < 4; ++i) {
        const int p = t + 256 * i, row = p >> 3;
        const int col = ((p & 7) ^ (row & 7)) * 8;
        asrc[i] = A + (size_t)(m0 + row) * lda + col;
        adst[i] = ldsA + p * 8;
    }
    #pragma unroll
    for (int i = 0; i < 8; ++i) {
        const int p = t + 256 * i, row = p >> 3;
        const int col = ((p & 7) ^ (row & 7)) * 8;
        bsrc[i] = B + (size_t)(n0 + row) * ldb + col;
        bdst[i] = ldsB + p * 8;
    }

    const _Float16* fa = ldsA + (wm + lrow) * 64;
    const _Float16* fb = ldsB + (wn + lrow) * 64;

    for (int k0 = 0; k0 < K; k0 += 64) {
        #pragma unroll
        for (int i = 0; i < 4; ++i) lds_load16(asrc[i] + k0, adst[i]);
        #pragma unroll
        for (int i = 0; i < 8; ++i) lds_load16(bsrc[i] + k0, bdst[i]);
        __syncthreads();

        #pragma unroll
        for (int s = 0; s < 2; ++s) {
            const int co = (((s * 4 + q) ^ xk) * 8);
            half8 af[4], bf[8];
            #pragma unroll
            for (int i = 0; i < 4; ++i) af[i] = *(const half8*)(fa + i * 1024 + co);
            #pragma unroll
            for (int i = 0; i < 8; ++i) bf[i] = *(const half8*)(fb + i * 1024 + co);
            #pragma unroll
            for (int ni = 0; ni < 8; ++ni)
                #pragma unroll
                for (int mi = 0; mi < 4; ++mi)
                    acc[mi][ni] = __builtin_amdgcn_mfma_f32_16x16x32_f16(
                        af[mi], bf[ni], acc[mi][ni], 0, 0, 0);
        }
        __syncthreads();
    }
}

// ---------------------------------------------------------------------------
// 256x256-tile 8-wave NT GEMM core v3 (verbatim R16) — used by s and pv.
// ---------------------------------------------------------------------------
__device__ __forceinline__ void gemm256_core(const _Float16* __restrict__ A,
                                             const _Float16* __restrict__ B,
                                             int ktiles, int lda, int ldb,
                                             int m0, int n0,
                                             _Float16* ldsA, _Float16* ldsB,
                                             floatx4 acc[8][4])
{
    const int t    = threadIdx.x;        // 0..511
    const int lane = t & 63;
    const int wr   = (t >> 6) >> 2;      // 0..1
    const int wc   = (t >> 6) & 3;       // 0..3
    const int lrow = lane & 15;
    const int q    = lane >> 4;
    const int xk   = lrow & 7;

    const _Float16* asrc[4]; _Float16* adst[4];
    const _Float16* bsrc[4]; _Float16* bdst[4];
    #pragma unroll
    for (int i = 0; i < 4; ++i) {
        const int p = t + 512 * i, row = p >> 3, c8 = p & 7;
        const int col = (c8 ^ (row & 7)) * 8;
        asrc[i] = A + (size_t)(m0 + row) * lda + col;
        adst[i] = ldsA + row * 64 + c8 * 8;
        bsrc[i] = B + (size_t)(n0 + row) * ldb + col;
        bdst[i] = ldsB + row * 64 + c8 * 8;
    }

    const int faoff = (wr * 128 + lrow) * 64;
    const int fboff = (wc * 64 + lrow) * 64;

#define STAGE(T_) do { const size_t ko_ = (size_t)(T_) * 64; \
        const int bo_ = ((T_) & 1) * 16384; \
        _Pragma("unroll") \
        for (int i_ = 0; i_ < 4; ++i_) { \
            lds_load16(asrc[i_] + ko_, adst[i_] + bo_); \
            lds_load16(bsrc[i_] + ko_, bdst[i_] + bo_); } } while (0)

    STAGE(0);
    asm volatile("s_waitcnt vmcnt(0)" ::: "memory");
    __builtin_amdgcn_s_barrier();

    for (int T = 0; T < ktiles; ++T) {
        if (T + 1 < ktiles) STAGE(T + 1);

        const _Float16* fa = ldsA + (T & 1) * 16384 + faoff;
        const _Float16* fb = ldsB + (T & 1) * 16384 + fboff;
        #pragma unroll
        for (int s = 0; s < 2; ++s) {
            const int co = (((s * 4 + q) ^ xk) * 8);
            half8 af[8], bf[4];
            #pragma unroll
            for (int mi = 0; mi < 8; ++mi) af[mi] = *(const half8*)(fa + mi * 1024 + co);
            #pragma unroll
            for (int ni = 0; ni < 4; ++ni) bf[ni] = *(const half8*)(fb + ni * 1024 + co);
            #pragma unroll
            for (int ni = 0; ni < 4; ++ni)
                #pragma unroll
                for (int mi = 0; mi < 8; ++mi)
                    acc[mi][ni] = __builtin_amdgcn_mfma_f32_16x16x32_f16(
                        af[mi], bf[ni], acc[mi][ni], 0, 0, 0);
        }

        if (T + 1 < ktiles) {
            asm volatile("s_waitcnt vmcnt(0)" ::: "memory");
        }
        __builtin_amdgcn_s_barrier();
    }
#undef STAGE
}

// ---------------------------------------------------------------------------
// K0: prep v2 — grid 2048 x 256 thr.
//   phase 1: xh = (fp16)x, exact cover: thread handles 8 floats (32B->16B).
//   phase 2: W transpose in 64x64 tiles; 768 tasks on blocks 0..767.
// ---------------------------------------------------------------------------
__global__ void __launch_bounds__(256) prep_kernel(const float* __restrict__ x,
                                                   const float* __restrict__ W0,
                                                   const float* __restrict__ W1,
                                                   const float* __restrict__ W2,
                                                   _Float16* __restrict__ xh,
                                                   _Float16* __restrict__ Wt)
{
    __shared__ _Float16 ldsT[64][72];   // 9216 B; rows 144B (16B-aligned)
    const int t = threadIdx.x;

    // phase 1: x conversion. 2048*256 threads * 8 floats = 4096*1024 exact.
    {
        const size_t i = ((size_t)blockIdx.x * 256 + t) * 8;
        float4 v0 = *(const float4*)(x + i);
        float4 v1 = *(const float4*)(x + i + 4);
        half8 h;
        h[0] = (_Float16)v0.x; h[1] = (_Float16)v0.y;
        h[2] = (_Float16)v0.z; h[3] = (_Float16)v0.w;
        h[4] = (_Float16)v1.x; h[5] = (_Float16)v1.y;
        h[6] = (_Float16)v1.z; h[7] = (_Float16)v1.w;
        *(half8*)(xh + i) = h;
    }

    // phase 2: W transpose, 64x64 tiles. 3 z * 16 * 16 = 768 tasks.
    const int w = blockIdx.x;
    if (w < 768) {
        const int z = w >> 8, r = w & 255;
        const int nb = (r & 15) * 64, kb = (r >> 4) * 64;
        const float* W = (z == 0) ? W0 : (z == 1) ? W1 : W2;
        _Float16* outw = Wt + (size_t)z * DIM * DIM;

        // load: 64 k-rows x 64 n-cols; 4 thr/row, 16 floats each (coalesced 256B/row)
        const int krow = t >> 2, c0 = (t & 3) * 16;
        #pragma unroll
        for (int j4 = 0; j4 < 4; ++j4) {
            float4 v = *(const float4*)(W + (size_t)(kb + krow) * DIM + nb + c0 + j4 * 4);
            ldsT[c0 + j4 * 4 + 0][krow] = (_Float16)v.x;
            ldsT[c0 + j4 * 4 + 1][krow] = (_Float16)v.y;
            ldsT[c0 + j4 * 4 + 2][krow] = (_Float16)v.z;
            ldsT[c0 + j4 * 4 + 3][krow] = (_Float16)v.w;
        }
        __syncthreads();

        // store: 64 n-rows x 64 k-halfs; 4 thr/row, 32B each (contiguous)
        const int nrow = t >> 2, kc = (t & 3) * 16;
        half8 a = *(const half8*)&ldsT[nrow][kc];
        half8 b = *(const half8*)&ldsT[nrow][kc + 8];
        _Float16* dst = outw + (size_t)(nb + nrow) * DIM + kb + kc;
        *(half8*)(dst)     = a;
        *(half8*)(dst + 8) = b;
    }
}

// ---------------------------------------------------------------------------
// K1: QKV mixed-K wide grid (verbatim R9/R12, verified; 512 blocks = 2/CU).
// ---------------------------------------------------------------------------
__global__ void __launch_bounds__(256, 2)
qkv_kernel(const _Float16* __restrict__ xh,
           const _Float16* __restrict__ Wt,
           const float* __restrict__ bq,
           const float* __restrict__ bk,
           const float* __restrict__ bv,
           _Float16* __restrict__ qh,
           _Float16* __restrict__ kh,
           _Float16* __restrict__ vt0,
           _Float16* __restrict__ vt1)
{
    __shared__ _Float16 ldsA[128 * 64];
    __shared__ _Float16 ldsB[256 * 64];

    const int b = blockIdx.x;

    const _Float16* A; const _Float16* B;
    const float* bias; _Float16* outm;
    int m0, n0, ldc, K, kstart; bool bias_by_row, do_bias;

    if (b < 256) {
        const int z = b >> 7;            // 0:q 1:k
        const int g = b & 127;
        const int xcd = g & 7;
        const int j   = g >> 3;          // 0..15
        const int mt  = xcd * 4 + (j & 3);   // 32 m-tiles
        const int nt  = j >> 2;              // 4 n-tiles of 256
        m0 = mt * 128; n0 = nt * 256; ldc = DIM;
        K = DIM; kstart = 0; bias_by_row = false; do_bias = true;
        A = xh;
        B = (z == 0) ? Wt : Wt + DIM * DIM;
        bias = (z == 0) ? bq : bk;
        outm = (z == 0) ? qh : kh;
    } else {
        const int h = (b - 256) >> 7;    // k-half 0/1
        const int g = b & 127;
        const int xcd = g & 7;
        const int j   = g >> 3;          // 0..15
        m0 = xcd * 128;                  // 8 m-tiles (d-dim)
        n0 = j * 256;                    // 16 n-tiles (tokens)
        ldc = NTOK;
        K = DIM / 2; kstart = h * (DIM / 2);
        bias_by_row = true; do_bias = (h == 0);
        A = Wt + 2 * DIM * DIM; B = xh; bias = bv;
        outm = (h == 0) ? vt0 : vt1;
    }

    floatx4 acc[4][8];
    #pragma unroll
    for (int mi = 0; mi < 4; ++mi)
        #pragma unroll
        for (int ni = 0; ni < 8; ++ni)
            #pragma unroll
            for (int r = 0; r < 4; ++r) acc[mi][ni][r] = 0.0f;

    gemm_wide_core(A + kstart, B + kstart, K, DIM, DIM, m0, n0, ldsA, ldsB, acc);

    const int lane = threadIdx.x & 63;
    const int wid  = threadIdx.x >> 6;
    const int wm   = (wid >> 1) * 64;
    const int wn   = (wid & 1) * 128;
    const int lrow = lane & 15;
    const int q    = lane >> 4;
    #pragma unroll
    for (int mi = 0; mi < 4; ++mi) {
        #pragma unroll
        for (int ni = 0; ni < 8; ++ni) {
            const int gm = m0 + wm + mi * 16 + q * 4;
            const int gn = n0 + wn + ni * 16 + lrow;
            const float bcol = (!do_bias || bias_by_row) ? 0.0f : bias[gn];
            #pragma unroll
            for (int r = 0; r < 4; ++r) {
                float bb = do_bias ? (bias_by_row ? bias[gm + r] : bcol) : 0.0f;
                outm[(size_t)(gm + r) * ldc + gn] = (_Float16)(acc[mi][ni][r] + bb);
            }
        }
    }
}

// ---------------------------------------------------------------------------
// K2: combine v partials: vt = vt0 + vt1 (verbatim R9).
// ---------------------------------------------------------------------------
__global__ void __launch_bounds__(256) combine_v(const _Float16* __restrict__ vt0,
                                                 const _Float16* __restrict__ vt1,
                                                 _Float16* __restrict__ vt)
{
    size_t i = ((size_t)blockIdx.x * 256 + threadIdx.x) * 8;
    half8 a = *(const half8*)(vt0 + i);
    half8 b = *(const half8*)(vt1 + i);
    half8 o;
    #pragma unroll
    for (int k = 0; k < 8; ++k) o[k] = (_Float16)((float)a[k] + (float)b[k]);
    *(half8*)(vt + i) = o;
}

// ---------------------------------------------------------------------------
// K3: S-GEMM + fused exp + partial rowsums — R16 256x256 core (verbatim).
// grid 256 (16mt x 16ct), XCD-banded, 512 thr.
// rowsum partials: 64 per row = 16 ct x 4 waves(wc).
// ---------------------------------------------------------------------------
__global__ void __launch_bounds__(512) s_kernel(const _Float16* __restrict__ qh,
                                                const _Float16* __restrict__ kh,
                                                _Float16* __restrict__ P,
                                                float* __restrict__ rowsum_part)
{
    __shared__ _Float16 ldsA[2 * 256 * 64];   // 64 KiB
    __shared__ _Float16 ldsB[2 * 256 * 64];   // 64 KiB

    const int b   = blockIdx.x;
    const int xcd = b & 7;
    const int j   = b >> 3;              // 0..31
    const int mt  = xcd * 2 + (j & 1);   // 16 m-tiles of 256
    const int ct  = j >> 1;              // 16 n-tiles of 256
    const int m0  = mt * 256;
    const int n0  = ct * 256;

    floatx4 acc[8][4];
    #pragma unroll
    for (int mi = 0; mi < 8; ++mi)
        #pragma unroll
        for (int ni = 0; ni < 4; ++ni)
            #pragma unroll
            for (int r = 0; r < 4; ++r) acc[mi][ni][r] = 0.0f;

    gemm256_core(qh, kh, DIM / 64, DIM, DIM, m0, n0, ldsA, ldsB, acc);

    const int lane = threadIdx.x & 63;
    const int wr   = (threadIdx.x >> 6) >> 2;
    const int wc   = (threadIdx.x >> 6) & 3;
    const int lrow = lane & 15;
    const int q    = lane >> 4;

    #pragma unroll
    for (int mi = 0; mi < 8; ++mi) {
        #pragma unroll
        for (int r = 0; r < 4; ++r) {
            const int gm = m0 + wr * 128 + mi * 16 + q * 4 + r;
            float rs = 0.0f;
            #pragma unroll
            for (int ni = 0; ni < 4; ++ni) {
                const int gn = n0 + wc * 64 + ni * 16 + lrow;
                float e = __expf(acc[mi][ni][r] * 0.03125f - 8.0f);
                P[(size_t)gm * NTOK + gn] = (_Float16)e;
                rs += e;
            }
            rs += __shfl_xor(rs, 1, 64);
            rs += __shfl_xor(rs, 2, 64);
            rs += __shfl_xor(rs, 4, 64);
            rs += __shfl_xor(rs, 8, 64);
            if (lrow == 0) rowsum_part[(size_t)gm * 64 + ct * 4 + wc] = rs;
        }
    }
}

// ---------------------------------------------------------------------------
// K4: PV split-K=4 — R16 v3 core verbatim. grid 256 (4z x 16mt x 4ct).
// z=0 -> fp32 out raw; z=1..3 -> fp16 partials.
// ---------------------------------------------------------------------------
__global__ void __launch_bounds__(512) pv_kernel(const _Float16* __restrict__ P,
                                                 const _Float16* __restrict__ vt,
                                                 float* __restrict__ out,
                                                 _Float16* __restrict__ P1,
                                                 _Float16* __restrict__ P2,
                                                 _Float16* __restrict__ P3)
{
    __shared__ _Float16 ldsA[2 * 256 * 64];
    __shared__ _Float16 ldsB[2 * 256 * 64];

    const int b   = blockIdx.x;
    const int z   = b >> 6;              // 0..3
    const int g   = b & 63;
    const int xcd = g & 7;
    const int j   = g >> 3;              // 0..7
    const int mt  = xcd * 2 + (j & 1);   // 16 m-tiles of 256 (tokens)
    const int ct  = j >> 1;              // 4 n-tiles of 256 (dim)
    const int m0  = mt * 256;
    const int n0  = ct * 256;
    const int kstart = z * (NTOK / 4);

    floatx4 acc[8][4];
    #pragma unroll
    for (int mi = 0; mi < 8; ++mi)
        #pragma unroll
        for (int ni = 0; ni < 4; ++ni)
            #pragma unroll
            for (int r = 0; r < 4; ++r) acc[mi][ni][r] = 0.0f;

    gemm256_core(P + kstart, vt + kstart, (NTOK / 4) / 64, NTOK, NTOK, m0, n0,
                 ldsA, ldsB, acc);

    const int lane = threadIdx.x & 63;
    const int wr   = (threadIdx.x >> 6) >> 2;
    const int wc   = (threadIdx.x >> 6) & 3;
    const int lrow = lane & 15;
    const int q    = lane >> 4;

    _Float16* ph = (z == 1) ? P1 : (z == 2) ? P2 : P3;
    #pragma unroll
    for (int mi = 0; mi < 8; ++mi) {
        #pragma unroll
        for (int ni = 0; ni < 4; ++ni) {
            const int gm = m0 + wr * 128 + mi * 16 + q * 4;
            const int gn = n0 + wc * 64 + ni * 16 + lrow;
            #pragma unroll
            for (int r = 0; r < 4; ++r) {
                if (z == 0) out[(size_t)(gm + r) * DIM + gn] = acc[mi][ni][r];
                else        ph[(size_t)(gm + r) * DIM + gn] = (_Float16)acc[mi][ni][r];
            }
        }
    }
}

// ---------------------------------------------------------------------------
// K5: out = (out + P1 + P2 + P3) / rowsum. rowsum: 64 partials/row.
// ---------------------------------------------------------------------------
__global__ void __launch_bounds__(128) add_inv_kernel(float* __restrict__ out,
                                                      const _Float16* __restrict__ P1,
                                                      const _Float16* __restrict__ P2,
                                                      const _Float16* __restrict__ P3,
                                                      const float* __restrict__ rowsum_part)
{
    const int row = blockIdx.x;
    const int t = threadIdx.x;
    float v = rowsum_part[(size_t)row * 64 + (t & 63)];
    v += __shfl_xor(v, 32, 64);
    v += __shfl_xor(v, 16, 64);
    v += __shfl_xor(v, 8, 64);
    v += __shfl_xor(v, 4, 64);
    v += __shfl_xor(v, 2, 64);
    v += __shfl_xor(v, 1, 64);
    const float inv = 1.0f / v;

    size_t i = (size_t)row * DIM + (size_t)t * 8;
    #pragma unroll
    for (int h = 0; h < 2; ++h) {
        size_t ii = i + h * 4;
        float4 a = *(const float4*)(out + ii);
        half4v b1 = *(const half4v*)(P1 + ii);
        half4v b2 = *(const half4v*)(P2 + ii);
        half4v b3 = *(const half4v*)(P3 + ii);
        a.x = (a.x + (float)b1[0] + (float)b2[0] + (float)b3[0]) * inv;
        a.y = (a.y + (float)b1[1] + (float)b2[1] + (float)b3[1]) * inv;
        a.z = (a.z + (float)b1[2] + (float)b2[2] + (float)b3[2]) * inv;
        a.w = (a.w + (float)b1[3] + (float)b2[3] + (float)b3[3]) * inv;
        *(float4*)(out + ii) = a;
    }
}

// ---------------------------------------------------------------------------
// launch
// ---------------------------------------------------------------------------
extern "C" void kernel_launch(void* const* d_in, const int* in_sizes, int n_in,
                              void* d_out, int out_size, void* d_ws, size_t ws_size,
                              hipStream_t stream)
{
    const float* x  = (const float*)d_in[0];
    const float* Wq = (const float*)d_in[1];
    const float* Wk = (const float*)d_in[2];
    const float* Wv = (const float*)d_in[3];
    const float* bq = (const float*)d_in[4];
    const float* bk = (const float*)d_in[5];
    const float* bv = (const float*)d_in[6];
    float* out = (float*)d_out;
    char* ws = (char*)d_ws;

    // workspace layout (70 MB peak; R16 champion scheme, verbatim):
    //   0..8    xh   (dead after QKV)      -> rowsum_part @0 (1 MB, S phase)
    //   8..14   Wt   (dead after QKV)      -> P1 @2..10 (PV phase)
    //  14..22   qh   (dead after S)        -> P2 @11..19
    //  22..30   kh   (dead after S)        -> P3 @20..28
    //  30..38   vt   (alive through PV)
    //  38..46   vt0  (dead after combine; P overwrites in S phase)
    //  46..54   vt1  (dead after combine; P overwrites in S phase)
    //  38..70   P    (written in S, after vt0/vt1 dead)
    _Float16* xh  = (_Float16*)(ws);
    _Float16* Wt  = (_Float16*)(ws + (8ull  << 20));
    _Float16* qh  = (_Float16*)(ws + (14ull << 20));
    _Float16* kh  = (_Float16*)(ws + (22ull << 20));
    _Float16* vt  = (_Float16*)(ws + (30ull << 20));
    _Float16* vt0 = (_Float16*)(ws + (38ull << 20));
    _Float16* vt1 = (_Float16*)(ws + (46ull << 20));
    _Float16* P   = (_Float16*)(ws + (38ull << 20));
    float* rowsum_part = (float*)(ws);
    _Float16* P1  = (_Float16*)(ws + (2ull  << 20));
    _Float16* P2  = (_Float16*)(ws + (11ull << 20));
    _Float16* P3  = (_Float16*)(ws + (20ull << 20));

    prep_kernel<<<dim3(2048), 256, 0, stream>>>(x, Wq, Wk, Wv, xh, Wt);
    qkv_kernel<<<dim3(512), 256, 0, stream>>>(xh, Wt, bq, bk, bv, qh, kh, vt0, vt1);
    combine_v<<<dim3(NTOK * DIM / (256 * 8)), 256, 0, stream>>>(vt0, vt1, vt);
    s_kernel<<<dim3(256), 512, 0, stream>>>(qh, kh, P, rowsum_part);
    pv_kernel<<<dim3(256), 512, 0, stream>>>(P, vt, out, P1, P2, P3);
    add_inv_kernel<<<dim3(NTOK), 128, 0, stream>>>(out, P1, P2, P3, rowsum_part);
}

// Round 11
// 214.082 us; speedup vs baseline: 1.0734x; 1.0101x over previous
//
#include <hip/hip_runtime.h>
#include <hip/hip_fp16.h>
#include <cstdint>
#include <cstddef>

// ---------------------------------------------------------------------------
// SelfAttentionV2: out = softmax((x Wq + bq)(x Wk + bk)^T / 32) (x Wv + bv)
// N=4096, D=1024. fp32 in/out, fp16 MFMA internal.
// R23: exact R16 champion (209.4us) with ONE change: s_kernel XCD banding
//   re-mapped from 2mt x 16ct (qh 1MB + kh 8MB = 9MB > 4MB L2, kh thrash;
//   FETCH 36.9MB vs 16 ideal) to 4mt x 8ct (2MB + 4MB = 6MB).
//   Mapping: a=xcd>>1 -> mt quad, bb=xcd&1 -> ct octet, j=b>>3 in [0,32):
//   mt = a*4 + (j&3), ct = bb*8 + (j>>2). Bijective; rowsum idx unchanged.
//   prep reverted to champion (R22's BW-clean rewrite was null -> prep
//   was never the bottleneck). Everything else verbatim R16.
// ---------------------------------------------------------------------------

#define NTOK 4096
#define DIM  1024

typedef _Float16 half8  __attribute__((ext_vector_type(8)));
typedef _Float16 half4v __attribute__((ext_vector_type(4)));
typedef float    floatx4 __attribute__((ext_vector_type(4)));

#define GLOBAL_AS __attribute__((address_space(1)))
#define LDS_AS    __attribute__((address_space(3)))

__device__ __forceinline__ void lds_load16(const _Float16* gsrc, _Float16* ldst) {
    __builtin_amdgcn_global_load_lds((GLOBAL_AS void*)gsrc, (LDS_AS void*)ldst, 16, 0, 0);
}

// ---------------------------------------------------------------------------
// WIDE 4-WAVE NT GEMM core (verbatim R4/R9/R11, verified) — used by qkv.
// ---------------------------------------------------------------------------
__device__ __forceinline__ void gemm_wide_core(const _Float16* __restrict__ A,
                                               const _Float16* __restrict__ B,
                                               int K, int lda, int ldb,
                                               int m0, int n0,
                                               _Float16* ldsA, _Float16* ldsB,
                                               floatx4 acc[4][8])
{
    const int t    = threadIdx.x;
    const int lane = t & 63;
    const int wid  = t >> 6;
    const int wm   = (wid >> 1) * 64;
    const int wn   = (wid & 1) * 128;
    const int lrow = lane & 15;
    const int q    = lane >> 4;
    const int xk   = lrow & 7;

    const _Float16* asrc[4]; _Float16* adst[4];
    const _Float16* bsrc[8]; _Float16* bdst[8];
    #pragma unroll
    for (int i = 0; i < 4; ++i) {
        const int p = t + 256 * i, row = p >> 3;
        const int col = ((p & 7) ^ (row & 7)) * 8;
        asrc[i] = A + (size_t)(m0 + row) * lda + col;
        adst[i] = ldsA + p * 8;
    }
    #pragma unroll
    for (int i = 0; i < 8; ++i) {
        const int p = t + 256 * i, row = p >> 3;
        const int col = ((p & 7) ^ (row & 7)) * 8;
        bsrc[i] = B + (size_t)(n0 + row) * ldb + col;
        bdst[i] = ldsB + p * 8;
    }

    const _Float16* fa = ldsA + (wm + lrow) * 64;
    const _Float16* fb = ldsB + (wn + lrow) * 64;

    for (int k0 = 0; k0 < K; k0 += 64) {
        #pragma unroll
        for (int i = 0; i < 4; ++i) lds_load16(asrc[i] + k0, adst[i]);
        #pragma unroll
        for (int i = 0; i < 8; ++i) lds_load16(bsrc[i] + k0, bdst[i]);
        __syncthreads();

        #pragma unroll
        for (int s = 0; s < 2; ++s) {
            const int co = (((s * 4 + q) ^ xk) * 8);
            half8 af[4], bf[8];
            #pragma unroll
            for (int i = 0; i < 4; ++i) af[i] = *(const half8*)(fa + i * 1024 + co);
            #pragma unroll
            for (int i = 0; i < 8; ++i) bf[i] = *(const half8*)(fb + i * 1024 + co);
            #pragma unroll
            for (int ni = 0; ni < 8; ++ni)
                #pragma unroll
                for (int mi = 0; mi < 4; ++mi)
                    acc[mi][ni] = __builtin_amdgcn_mfma_f32_16x16x32_f16(
                        af[mi], bf[ni], acc[mi][ni], 0, 0, 0);
        }
        __syncthreads();
    }
}

// ---------------------------------------------------------------------------
// 256x256-tile 8-wave NT GEMM core v3 (verbatim R16) — used by s and pv.
// ---------------------------------------------------------------------------
__device__ __forceinline__ void gemm256_core(const _Float16* __restrict__ A,
                                             const _Float16* __restrict__ B,
                                             int ktiles, int lda, int ldb,
                                             int m0, int n0,
                                             _Float16* ldsA, _Float16* ldsB,
                                             floatx4 acc[8][4])
{
    const int t    = threadIdx.x;        // 0..511
    const int lane = t & 63;
    const int wr   = (t >> 6) >> 2;      // 0..1
    const int wc   = (t >> 6) & 3;       // 0..3
    const int lrow = lane & 15;
    const int q    = lane >> 4;
    const int xk   = lrow & 7;

    const _Float16* asrc[4]; _Float16* adst[4];
    const _Float16* bsrc[4]; _Float16* bdst[4];
    #pragma unroll
    for (int i = 0; i < 4; ++i) {
        const int p = t + 512 * i, row = p >> 3, c8 = p & 7;
        const int col = (c8 ^ (row & 7)) * 8;
        asrc[i] = A + (size_t)(m0 + row) * lda + col;
        adst[i] = ldsA + row * 64 + c8 * 8;
        bsrc[i] = B + (size_t)(n0 + row) * ldb + col;
        bdst[i] = ldsB + row * 64 + c8 * 8;
    }

    const int faoff = (wr * 128 + lrow) * 64;
    const int fboff = (wc * 64 + lrow) * 64;

#define STAGE(T_) do { const size_t ko_ = (size_t)(T_) * 64; \
        const int bo_ = ((T_) & 1) * 16384; \
        _Pragma("unroll") \
        for (int i_ = 0; i_ < 4; ++i_) { \
            lds_load16(asrc[i_] + ko_, adst[i_] + bo_); \
            lds_load16(bsrc[i_] + ko_, bdst[i_] + bo_); } } while (0)

    STAGE(0);
    asm volatile("s_waitcnt vmcnt(0)" ::: "memory");
    __builtin_amdgcn_s_barrier();

    for (int T = 0; T < ktiles; ++T) {
        if (T + 1 < ktiles) STAGE(T + 1);

        const _Float16* fa = ldsA + (T & 1) * 16384 + faoff;
        const _Float16* fb = ldsB + (T & 1) * 16384 + fboff;
        #pragma unroll
        for (int s = 0; s < 2; ++s) {
            const int co = (((s * 4 + q) ^ xk) * 8);
            half8 af[8], bf[4];
            #pragma unroll
            for (int mi = 0; mi < 8; ++mi) af[mi] = *(const half8*)(fa + mi * 1024 + co);
            #pragma unroll
            for (int ni = 0; ni < 4; ++ni) bf[ni] = *(const half8*)(fb + ni * 1024 + co);
            #pragma unroll
            for (int ni = 0; ni < 4; ++ni)
                #pragma unroll
                for (int mi = 0; mi < 8; ++mi)
                    acc[mi][ni] = __builtin_amdgcn_mfma_f32_16x16x32_f16(
                        af[mi], bf[ni], acc[mi][ni], 0, 0, 0);
        }

        if (T + 1 < ktiles) {
            asm volatile("s_waitcnt vmcnt(0)" ::: "memory");
        }
        __builtin_amdgcn_s_barrier();
    }
#undef STAGE
}

// ---------------------------------------------------------------------------
// K0: prep (verbatim R9 champion body, grid 3072).
// ---------------------------------------------------------------------------
__global__ void __launch_bounds__(128) prep_kernel(const float* __restrict__ x,
                                                   const float* __restrict__ W0,
                                                   const float* __restrict__ W1,
                                                   const float* __restrict__ W2,
                                                   _Float16* __restrict__ xh,
                                                   _Float16* __restrict__ Wt)
{
    __shared__ float tile[32 * 33];
    const int t = threadIdx.x;
    const int G = gridDim.x;

    for (size_t idx = (size_t)blockIdx.x * 128 + t; idx < (size_t)NTOK * DIM / 4;
         idx += (size_t)G * 128) {
        size_t i = idx * 4;
        float4 v = *(const float4*)(x + i);
        half4v h;
        h[0] = (_Float16)v.x; h[1] = (_Float16)v.y;
        h[2] = (_Float16)v.z; h[3] = (_Float16)v.w;
        *(half4v*)(xh + i) = h;
    }

    const int tx = t & 31, ty = t >> 5;   // ty in [0,4)
    for (int w = blockIdx.x; w < 3072; w += G) {
        const int z = w >> 10, r = w & 1023;
        const int nb = (r & 31) * 32, kb = (r >> 5) * 32;
        const float* W = (z == 0) ? W0 : (z == 1) ? W1 : W2;
        _Float16* outw = Wt + (size_t)z * DIM * DIM;
        #pragma unroll
        for (int i = 0; i < 32; i += 4)
            tile[(ty + i) * 33 + tx] = W[(size_t)(kb + ty + i) * DIM + nb + tx];
        __syncthreads();
        #pragma unroll
        for (int i = 0; i < 32; i += 4)
            outw[(size_t)(nb + ty + i) * DIM + kb + tx] =
                (_Float16)tile[tx * 33 + ty + i];
        __syncthreads();
    }
}

// ---------------------------------------------------------------------------
// K1: QKV mixed-K wide grid (verbatim R9/R12, verified; 512 blocks = 2/CU).
// ---------------------------------------------------------------------------
__global__ void __launch_bounds__(256, 2)
qkv_kernel(const _Float16* __restrict__ xh,
           const _Float16* __restrict__ Wt,
           const float* __restrict__ bq,
           const float* __restrict__ bk,
           const float* __restrict__ bv,
           _Float16* __restrict__ qh,
           _Float16* __restrict__ kh,
           _Float16* __restrict__ vt0,
           _Float16* __restrict__ vt1)
{
    __shared__ _Float16 ldsA[128 * 64];
    __shared__ _Float16 ldsB[256 * 64];

    const int b = blockIdx.x;

    const _Float16* A; const _Float16* B;
    const float* bias; _Float16* outm;
    int m0, n0, ldc, K, kstart; bool bias_by_row, do_bias;

    if (b < 256) {
        const int z = b >> 7;            // 0:q 1:k
        const int g = b & 127;
        const int xcd = g & 7;
        const int j   = g >> 3;          // 0..15
        const int mt  = xcd * 4 + (j & 3);   // 32 m-tiles
        const int nt  = j >> 2;              // 4 n-tiles of 256
        m0 = mt * 128; n0 = nt * 256; ldc = DIM;
        K = DIM; kstart = 0; bias_by_row = false; do_bias = true;
        A = xh;
        B = (z == 0) ? Wt : Wt + DIM * DIM;
        bias = (z == 0) ? bq : bk;
        outm = (z == 0) ? qh : kh;
    } else {
        const int h = (b - 256) >> 7;    // k-half 0/1
        const int g = b & 127;
        const int xcd = g & 7;
        const int j   = g >> 3;          // 0..15
        m0 = xcd * 128;                  // 8 m-tiles (d-dim)
        n0 = j * 256;                    // 16 n-tiles (tokens)
        ldc = NTOK;
        K = DIM / 2; kstart = h * (DIM / 2);
        bias_by_row = true; do_bias = (h == 0);
        A = Wt + 2 * DIM * DIM; B = xh; bias = bv;
        outm = (h == 0) ? vt0 : vt1;
    }

    floatx4 acc[4][8];
    #pragma unroll
    for (int mi = 0; mi < 4; ++mi)
        #pragma unroll
        for (int ni = 0; ni < 8; ++ni)
            #pragma unroll
            for (int r = 0; r < 4; ++r) acc[mi][ni][r] = 0.0f;

    gemm_wide_core(A + kstart, B + kstart, K, DIM, DIM, m0, n0, ldsA, ldsB, acc);

    const int lane = threadIdx.x & 63;
    const int wid  = threadIdx.x >> 6;
    const int wm   = (wid >> 1) * 64;
    const int wn   = (wid & 1) * 128;
    const int lrow = lane & 15;
    const int q    = lane >> 4;
    #pragma unroll
    for (int mi = 0; mi < 4; ++mi) {
        #pragma unroll
        for (int ni = 0; ni < 8; ++ni) {
            const int gm = m0 + wm + mi * 16 + q * 4;
            const int gn = n0 + wn + ni * 16 + lrow;
            const float bcol = (!do_bias || bias_by_row) ? 0.0f : bias[gn];
            #pragma unroll
            for (int r = 0; r < 4; ++r) {
                float bb = do_bias ? (bias_by_row ? bias[gm + r] : bcol) : 0.0f;
                outm[(size_t)(gm + r) * ldc + gn] = (_Float16)(acc[mi][ni][r] + bb);
            }
        }
    }
}

// ---------------------------------------------------------------------------
// K2: combine v partials: vt = vt0 + vt1 (verbatim R9).
// ---------------------------------------------------------------------------
__global__ void __launch_bounds__(256) combine_v(const _Float16* __restrict__ vt0,
                                                 const _Float16* __restrict__ vt1,
                                                 _Float16* __restrict__ vt)
{
    size_t i = ((size_t)blockIdx.x * 256 + threadIdx.x) * 8;
    half8 a = *(const half8*)(vt0 + i);
    half8 b = *(const half8*)(vt1 + i);
    half8 o;
    #pragma unroll
    for (int k = 0; k < 8; ++k) o[k] = (_Float16)((float)a[k] + (float)b[k]);
    *(half8*)(vt + i) = o;
}

// ---------------------------------------------------------------------------
// K3: S-GEMM + fused exp + partial rowsums — R16 256x256 core with NEW
// 4mt x 8ct per-XCD banding (L2 working set 9MB -> 6MB).
// grid 256, 512 thr. rowsum partials: 64 per row = 16 ct x 4 waves(wc).
// ---------------------------------------------------------------------------
__global__ void __launch_bounds__(512) s_kernel(const _Float16* __restrict__ qh,
                                                const _Float16* __restrict__ kh,
                                                _Float16* __restrict__ P,
                                                float* __restrict__ rowsum_part)
{
    __shared__ _Float16 ldsA[2 * 256 * 64];   // 64 KiB
    __shared__ _Float16 ldsB[2 * 256 * 64];   // 64 KiB

    const int b   = blockIdx.x;
    const int xcd = b & 7;
    const int j   = b >> 3;              // 0..31
    const int a2  = xcd >> 1;            // mt quad 0..3
    const int bb  = xcd & 1;             // ct octet 0..1
    const int mt  = a2 * 4 + (j & 3);    // 16 m-tiles of 256
    const int ct  = bb * 8 + (j >> 2);   // 16 n-tiles of 256
    const int m0  = mt * 256;
    const int n0  = ct * 256;

    floatx4 acc[8][4];
    #pragma unroll
    for (int mi = 0; mi < 8; ++mi)
        #pragma unroll
        for (int ni = 0; ni < 4; ++ni)
            #pragma unroll
            for (int r = 0; r < 4; ++r) acc[mi][ni][r] = 0.0f;

    gemm256_core(qh, kh, DIM / 64, DIM, DIM, m0, n0, ldsA, ldsB, acc);

    const int lane = threadIdx.x & 63;
    const int wr   = (threadIdx.x >> 6) >> 2;
    const int wc   = (threadIdx.x >> 6) & 3;
    const int lrow = lane & 15;
    const int q    = lane >> 4;

    #pragma unroll
    for (int mi = 0; mi < 8; ++mi) {
        #pragma unroll
        for (int r = 0; r < 4; ++r) {
            const int gm = m0 + wr * 128 + mi * 16 + q * 4 + r;
            float rs = 0.0f;
            #pragma unroll
            for (int ni = 0; ni < 4; ++ni) {
                const int gn = n0 + wc * 64 + ni * 16 + lrow;
                float e = __expf(acc[mi][ni][r] * 0.03125f - 8.0f);
                P[(size_t)gm * NTOK + gn] = (_Float16)e;
                rs += e;
            }
            rs += __shfl_xor(rs, 1, 64);
            rs += __shfl_xor(rs, 2, 64);
            rs += __shfl_xor(rs, 4, 64);
            rs += __shfl_xor(rs, 8, 64);
            if (lrow == 0) rowsum_part[(size_t)gm * 64 + ct * 4 + wc] = rs;
        }
    }
}

// ---------------------------------------------------------------------------
// K4: PV split-K=4 — R16 v3 core verbatim. grid 256 (4z x 16mt x 4ct).
// z=0 -> fp32 out raw; z=1..3 -> fp16 partials.
// ---------------------------------------------------------------------------
__global__ void __launch_bounds__(512) pv_kernel(const _Float16* __restrict__ P,
                                                 const _Float16* __restrict__ vt,
                                                 float* __restrict__ out,
                                                 _Float16* __restrict__ P1,
                                                 _Float16* __restrict__ P2,
                                                 _Float16* __restrict__ P3)
{
    __shared__ _Float16 ldsA[2 * 256 * 64];
    __shared__ _Float16 ldsB[2 * 256 * 64];

    const int b   = blockIdx.x;
    const int z   = b >> 6;              // 0..3
    const int g   = b & 63;
    const int xcd = g & 7;
    const int j   = g >> 3;              // 0..7
    const int mt  = xcd * 2 + (j & 1);   // 16 m-tiles of 256 (tokens)
    const int ct  = j >> 1;              // 4 n-tiles of 256 (dim)
    const int m0  = mt * 256;
    const int n0  = ct * 256;
    const int kstart = z * (NTOK / 4);

    floatx4 acc[8][4];
    #pragma unroll
    for (int mi = 0; mi < 8; ++mi)
        #pragma unroll
        for (int ni = 0; ni < 4; ++ni)
            #pragma unroll
            for (int r = 0; r < 4; ++r) acc[mi][ni][r] = 0.0f;

    gemm256_core(P + kstart, vt + kstart, (NTOK / 4) / 64, NTOK, NTOK, m0, n0,
                 ldsA, ldsB, acc);

    const int lane = threadIdx.x & 63;
    const int wr   = (threadIdx.x >> 6) >> 2;
    const int wc   = (threadIdx.x >> 6) & 3;
    const int lrow = lane & 15;
    const int q    = lane >> 4;

    _Float16* ph = (z == 1) ? P1 : (z == 2) ? P2 : P3;
    #pragma unroll
    for (int mi = 0; mi < 8; ++mi) {
        #pragma unroll
        for (int ni = 0; ni < 4; ++ni) {
            const int gm = m0 + wr * 128 + mi * 16 + q * 4;
            const int gn = n0 + wc * 64 + ni * 16 + lrow;
            #pragma unroll
            for (int r = 0; r < 4; ++r) {
                if (z == 0) out[(size_t)(gm + r) * DIM + gn] = acc[mi][ni][r];
                else        ph[(size_t)(gm + r) * DIM + gn] = (_Float16)acc[mi][ni][r];
            }
        }
    }
}

// ---------------------------------------------------------------------------
// K5: out = (out + P1 + P2 + P3) / rowsum. rowsum: 64 partials/row.
// ---------------------------------------------------------------------------
__global__ void __launch_bounds__(128) add_inv_kernel(float* __restrict__ out,
                                                      const _Float16* __restrict__ P1,
                                                      const _Float16* __restrict__ P2,
                                                      const _Float16* __restrict__ P3,
                                                      const float* __restrict__ rowsum_part)
{
    const int row = blockIdx.x;
    const int t = threadIdx.x;
    float v = rowsum_part[(size_t)row * 64 + (t & 63)];
    v += __shfl_xor(v, 32, 64);
    v += __shfl_xor(v, 16, 64);
    v += __shfl_xor(v, 8, 64);
    v += __shfl_xor(v, 4, 64);
    v += __shfl_xor(v, 2, 64);
    v += __shfl_xor(v, 1, 64);
    const float inv = 1.0f / v;

    size_t i = (size_t)row * DIM + (size_t)t * 8;
    #pragma unroll
    for (int h = 0; h < 2; ++h) {
        size_t ii = i + h * 4;
        float4 a = *(const float4*)(out + ii);
        half4v b1 = *(const half4v*)(P1 + ii);
        half4v b2 = *(const half4v*)(P2 + ii);
        half4v b3 = *(const half4v*)(P3 + ii);
        a.x = (a.x + (float)b1[0] + (float)b2[0] + (float)b3[0]) * inv;
        a.y = (a.y + (float)b1[1] + (float)b2[1] + (float)b3[1]) * inv;
        a.z = (a.z + (float)b1[2] + (float)b2[2] + (float)b3[2]) * inv;
        a.w = (a.w + (float)b1[3] + (float)b2[3] + (float)b3[3]) * inv;
        *(float4*)(out + ii) = a;
    }
}

// ---------------------------------------------------------------------------
// launch
// ---------------------------------------------------------------------------
extern "C" void kernel_launch(void* const* d_in, const int* in_sizes, int n_in,
                              void* d_out, int out_size, void* d_ws, size_t ws_size,
                              hipStream_t stream)
{
    const float* x  = (const float*)d_in[0];
    const float* Wq = (const float*)d_in[1];
    const float* Wk = (const float*)d_in[2];
    const float* Wv = (const float*)d_in[3];
    const float* bq = (const float*)d_in[4];
    const float* bk = (const float*)d_in[5];
    const float* bv = (const float*)d_in[6];
    float* out = (float*)d_out;
    char* ws = (char*)d_ws;

    // workspace layout (70 MB peak; R16 champion scheme, verbatim):
    //   0..8    xh   (dead after QKV)      -> rowsum_part @0 (1 MB, S phase)
    //   8..14   Wt   (dead after QKV)      -> P1 @2..10 (PV phase)
    //  14..22   qh   (dead after S)        -> P2 @11..19
    //  22..30   kh   (dead after S)        -> P3 @20..28
    //  30..38   vt   (alive through PV)
    //  38..46   vt0  (dead after combine; P overwrites in S phase)
    //  46..54   vt1  (dead after combine; P overwrites in S phase)
    //  38..70   P    (written in S, after vt0/vt1 dead)
    _Float16* xh  = (_Float16*)(ws);
    _Float16* Wt  = (_Float16*)(ws + (8ull  << 20));
    _Float16* qh  = (_Float16*)(ws + (14ull << 20));
    _Float16* kh  = (_Float16*)(ws + (22ull << 20));
    _Float16* vt  = (_Float16*)(ws + (30ull << 20));
    _Float16* vt0 = (_Float16*)(ws + (38ull << 20));
    _Float16* vt1 = (_Float16*)(ws + (46ull << 20));
    _Float16* P   = (_Float16*)(ws + (38ull << 20));
    float* rowsum_part = (float*)(ws);
    _Float16* P1  = (_Float16*)(ws + (2ull  << 20));
    _Float16* P2  = (_Float16*)(ws + (11ull << 20));
    _Float16* P3  = (_Float16*)(ws + (20ull << 20));

    prep_kernel<<<dim3(3072), 128, 0, stream>>>(x, Wq, Wk, Wv, xh, Wt);
    qkv_kernel<<<dim3(512), 256, 0, stream>>>(xh, Wt, bq, bk, bv, qh, kh, vt0, vt1);
    combine_v<<<dim3(NTOK * DIM / (256 * 8)), 256, 0, stream>>>(vt0, vt1, vt);
    s_kernel<<<dim3(256), 512, 0, stream>>>(qh, kh, P, rowsum_part);
    pv_kernel<<<dim3(256), 512, 0, stream>>>(P, vt, out, P1, P2, P3);
    add_inv_kernel<<<dim3(NTOK), 128, 0, stream>>>(out, P1, P2, P3, rowsum_part);
}